// Round 14
// baseline (2635.190 us; speedup 1.0000x reference)
//
#include <hip/hip_runtime.h>
#include <hip/hip_cooperative_groups.h>
#include <math.h>

namespace cg = cooperative_groups;

#define TT   24
#define NN   10000
#define DIN  128
#define H1C  256
#define H2C  128
#define OUTD 100
#define FLATSZ (NN*H2C)

typedef _Float16 f16;
typedef _Float16 f16x4 __attribute__((ext_vector_type(4)));
typedef _Float16 f16x8 __attribute__((ext_vector_type(8)));
typedef float    f32x4 __attribute__((ext_vector_type(4)));
typedef int      i32x2 __attribute__((ext_vector_type(2)));

__device__ __forceinline__ float sigmoidf_(float x){ return 1.0f/(1.0f+expf(-x)); }

// ---------------- small utility kernels ----------------

__global__ __launch_bounds__(256) void cast_f16_kernel(const float4* __restrict__ in,
                                                       f16x4* __restrict__ out, int n4){
  int i = blockIdx.x*256 + threadIdx.x;
  if (i < n4){
    float4 v = in[i];
    f16x4 o; o[0]=(f16)v.x; o[1]=(f16)v.y; o[2]=(f16)v.z; o[3]=(f16)v.w;
    out[i] = o;
  }
}

__global__ __launch_bounds__(256) void init_kernel(int* __restrict__ cnt, int* __restrict__ cursor,
                                                   float* __restrict__ logits, int n){
  int i = blockIdx.x*256 + threadIdx.x;
  if (i < n){ cnt[i] = 0; cursor[i] = 0; }
  if (i < OUTD) logits[i] = 0.0f;
}

__global__ __launch_bounds__(256) void count_kernel(const int* __restrict__ ei, int* __restrict__ cnt, int E){
  int e = blockIdx.x*256 + threadIdx.x;
  if (e < E) atomicAdd(&cnt[ei[E + e]], 1);
}

__global__ __launch_bounds__(256) void dis_kernel(const int* __restrict__ cnt, float* __restrict__ dis, int n){
  int i = blockIdx.x*256 + threadIdx.x;
  if (i < n) dis[i] = rsqrtf((float)(cnt[i] + 1));   // +1 self-loop
}

__global__ __launch_bounds__(256) void scan_kernel(const int* __restrict__ cnt, int* __restrict__ off, int n){
  __shared__ int sums[256];
  const int tid = threadIdx.x;
  const int CH  = 40;
  const int base = tid*CH;
  int s = 0;
  for (int i = 0; i < CH; ++i){ int idx = base + i; if (idx < n) s += cnt[idx]; }
  sums[tid] = s; __syncthreads();
  for (int d = 1; d < 256; d <<= 1){
    int v = (tid >= d) ? sums[tid - d] : 0;
    __syncthreads();
    sums[tid] += v;
    __syncthreads();
  }
  int run = (tid == 0) ? 0 : sums[tid - 1];
  for (int i = 0; i < CH; ++i){
    int idx = base + i;
    if (idx < n){ off[idx] = run; run += cnt[idx]; }
  }
  if (tid == 0) off[n] = sums[255];
}

__global__ __launch_bounds__(256) void scatter_kernel(const int* __restrict__ ei, const float* __restrict__ dis,
                                                      const int* __restrict__ off, int* __restrict__ cursor,
                                                      int2* __restrict__ pe, int E){
  int e = blockIdx.x*256 + threadIdx.x;
  if (e < E){
    int r = ei[e];
    int c = ei[E + e];
    int pos = off[c] + atomicAdd(&cursor[c], 1);
    pe[pos] = make_int2(r, __float_as_int(dis[r]*dis[c]));
  }
}

// ---------------- layer-1 GRU chain: cooperative, phase-locked blocks ----------------
// 157 blocks x 512 thr (8 col-groups x 64 rows). Block owns 64 rows for all 24 t.
// grid.sync() per step keeps all blocks reading the same weight region -> L2-resident weights.
// No cross-block data flow (h block-local): sync is a performance device only.
__global__ __launch_bounds__(512, 2) void gru1_chain_kernel(
    const float* __restrict__ x, const f16* __restrict__ Wih,
    const f16* __restrict__ Whh, const float* __restrict__ bih,
    const float* __restrict__ bhh, f16* __restrict__ h1all)
{
  cg::grid_group gg = cg::this_grid();
  constexpr int H  = H1C;      // 256
  constexpr int LP = H + 8;    // 264 f16 pitch (hl)
  constexpr int XP = DIN + 8;  // 136 f16 pitch (xl)
  __shared__ __align__(16) f16 hl[64*LP];   // 33.8 KB
  __shared__ __align__(16) f16 xl[64*XP];   // 17.4 KB

  const int tid  = threadIdx.x;
  const int lane = tid & 63;
  const int w    = tid >> 6;        // 0..7 col group (32 cols each)
  const int lr   = lane & 15;
  const int lk8  = (lane >> 4)*8;
  const int r0   = (lane >> 4)*4;
  const int row_base = blockIdx.x*64;

  for (int k = tid*8; k < 64*LP; k += 512*8)
    *(f16x8*)&hl[k] = (f16x8){0,0,0,0,0,0,0,0};

  int lrow[4];
  #pragma unroll
  for (int mi = 0; mi < 4; ++mi) lrow[mi] = mi*16 + lr;

  int colv[2], bxo[2][3], bho[2][3];
  float bR[2], bZ[2], bNi[2], bNh[2];
  #pragma unroll
  for (int ci = 0; ci < 2; ++ci){
    const int col = w*32 + ci*16 + lr;
    colv[ci] = col;
    #pragma unroll
    for (int g = 0; g < 3; ++g){
      bxo[ci][g] = (g*H + col)*DIN + lk8;
      bho[ci][g] = (g*H + col)*H   + lk8;
    }
    bR[ci]  = bih[col]       + bhh[col];
    bZ[ci]  = bih[H+col]     + bhh[H+col];
    bNi[ci] = bih[2*H+col];
    bNh[ci] = bhh[2*H+col];
  }

  float hst[4][4][2] = {};   // [mi][rr][ci] fp32 state, thread-owned across t
  __syncthreads();

  for (int t = 0; t < TT; ++t){
    // ---- stage x tile (64 rows x 128 f32 -> f16), nt loads ----
    {
      const float* xg = x + (size_t)t*NN*DIN;
      #pragma unroll
      for (int s = 0; s < 4; ++s){
        const int idx = s*512 + tid;       // 0..2047
        const int row = idx >> 5;
        const int c4  = (idx & 31)*4;
        int gr = row_base + row; if (gr >= NN) gr = NN-1;
        const f32x4 v = __builtin_nontemporal_load((const f32x4*)&xg[(size_t)gr*DIN + c4]);
        f16x4 o; o[0]=(f16)v[0]; o[1]=(f16)v[1]; o[2]=(f16)v[2]; o[3]=(f16)v[3];
        *(f16x4*)&xl[row*XP + c4] = o;
      }
    }
    __syncthreads();   // xl ready; hl stable

    f32x4 acc[4][2][4] = {};   // [mi][ci][0=r,1=z,2=n_x,3=n_h]

    // x part, K = 128 (A from LDS)
    #pragma unroll
    for (int k0 = 0; k0 < DIN; k0 += 32){
      f16x8 a[4], b[2][3];
      #pragma unroll
      for (int mi = 0; mi < 4; ++mi) a[mi] = *(const f16x8*)&xl[lrow[mi]*XP + k0 + lk8];
      #pragma unroll
      for (int ci = 0; ci < 2; ++ci)
        #pragma unroll
        for (int g = 0; g < 3; ++g) b[ci][g] = *(const f16x8*)(Wih + bxo[ci][g] + k0);
      #pragma unroll
      for (int mi = 0; mi < 4; ++mi)
        #pragma unroll
        for (int ci = 0; ci < 2; ++ci){
          acc[mi][ci][0] = __builtin_amdgcn_mfma_f32_16x16x32_f16(a[mi], b[ci][0], acc[mi][ci][0], 0,0,0);
          acc[mi][ci][1] = __builtin_amdgcn_mfma_f32_16x16x32_f16(a[mi], b[ci][1], acc[mi][ci][1], 0,0,0);
          acc[mi][ci][2] = __builtin_amdgcn_mfma_f32_16x16x32_f16(a[mi], b[ci][2], acc[mi][ci][2], 0,0,0);
        }
    }
    // h part, K = 256 (A from LDS)
    #pragma unroll
    for (int k0 = 0; k0 < H; k0 += 32){
      f16x8 a[4], b[2][3];
      #pragma unroll
      for (int mi = 0; mi < 4; ++mi) a[mi] = *(const f16x8*)&hl[lrow[mi]*LP + k0 + lk8];
      #pragma unroll
      for (int ci = 0; ci < 2; ++ci)
        #pragma unroll
        for (int g = 0; g < 3; ++g) b[ci][g] = *(const f16x8*)(Whh + bho[ci][g] + k0);
      #pragma unroll
      for (int mi = 0; mi < 4; ++mi)
        #pragma unroll
        for (int ci = 0; ci < 2; ++ci){
          acc[mi][ci][0] = __builtin_amdgcn_mfma_f32_16x16x32_f16(a[mi], b[ci][0], acc[mi][ci][0], 0,0,0);
          acc[mi][ci][1] = __builtin_amdgcn_mfma_f32_16x16x32_f16(a[mi], b[ci][1], acc[mi][ci][1], 0,0,0);
          acc[mi][ci][3] = __builtin_amdgcn_mfma_f32_16x16x32_f16(a[mi], b[ci][2], acc[mi][ci][3], 0,0,0);
        }
    }
    __syncthreads();   // all reads of hl/xl done
    // epilogue: gates + register state + hl update
    #pragma unroll
    for (int mi = 0; mi < 4; ++mi){
      #pragma unroll
      for (int rr = 0; rr < 4; ++rr){
        const int rl = mi*16 + r0 + rr;
        #pragma unroll
        for (int ci = 0; ci < 2; ++ci){
          const int col = colv[ci];
          const float rg = sigmoidf_(acc[mi][ci][0][rr] + bR[ci]);
          const float zg = sigmoidf_(acc[mi][ci][1][rr] + bZ[ci]);
          const float ng = tanhf(acc[mi][ci][2][rr] + bNi[ci] + rg*(acc[mi][ci][3][rr] + bNh[ci]));
          const float hv = (1.0f - zg)*ng + zg*hst[mi][rr][ci];
          hst[mi][rr][ci] = hv;
          hl[rl*LP + col] = (f16)hv;
        }
      }
    }
    __syncthreads();   // hl updated
    // coalesced nt copy LDS -> h1all[t]
    f16* ho = h1all + ((size_t)t*NN + row_base)*H;
    #pragma unroll
    for (int c = 0; c < 4; ++c){
      const int idx = c*512 + tid;         // 0..2047
      const int row = idx >> 5, seg = idx & 31;
      if (row_base + row < NN)
        __builtin_nontemporal_store(*(const f16x8*)&hl[row*LP + seg*8],
                                    (f16x8*)&ho[(size_t)row*H + seg*8]);
    }
    gg.sync();   // phase-lock all blocks (performance only; no cross-block data)
  }
}

// ---------------- layer-2 GRU chain: cooperative, phase-locked ----------------
__global__ __launch_bounds__(512, 2) void gru2_chain_kernel(
    const f16* __restrict__ x2all, const f16* __restrict__ Wih,
    const f16* __restrict__ Whh, const float* __restrict__ bih,
    const float* __restrict__ bhh, float* __restrict__ h2fin)
{
  cg::grid_group gg = cg::this_grid();
  constexpr int H   = H2C;     // 128
  constexpr int KX  = H1C;     // 256
  constexpr int LP  = H + 8;   // 136
  constexpr int X2P = KX + 8;  // 264
  __shared__ __align__(16) f16 hl[64*LP];    // 17.4 KB
  __shared__ __align__(16) f16 x2l[64*X2P];  // 33.8 KB

  const int tid  = threadIdx.x;
  const int lane = tid & 63;
  const int w    = tid >> 6;        // 0..7 col group (16 cols each)
  const int lr   = lane & 15;
  const int lk8  = (lane >> 4)*8;
  const int r0   = (lane >> 4)*4;
  const int row_base = blockIdx.x*64;

  for (int k = tid*8; k < 64*LP; k += 512*8)
    *(f16x8*)&hl[k] = (f16x8){0,0,0,0,0,0,0,0};

  int lrow[4];
  #pragma unroll
  for (int mi = 0; mi < 4; ++mi) lrow[mi] = mi*16 + lr;

  const int col = w*16 + lr;
  int bxo[3], bho[3];
  #pragma unroll
  for (int g = 0; g < 3; ++g){
    bxo[g] = (g*H + col)*KX + lk8;
    bho[g] = (g*H + col)*H  + lk8;
  }
  const float bR  = bih[col]       + bhh[col];
  const float bZ  = bih[H+col]     + bhh[H+col];
  const float bNi = bih[2*H+col];
  const float bNh = bhh[2*H+col];

  float hst[4][4] = {};   // [mi][rr]
  __syncthreads();

  for (int t = 0; t < TT; ++t){
    // ---- stage x2 tile (64 rows x 256 f16), nt loads ----
    {
      const f16* xg = x2all + (size_t)t*NN*KX;
      #pragma unroll
      for (int s = 0; s < 4; ++s){
        const int idx = s*512 + tid;       // 0..2047
        const int row = idx >> 5;
        const int sg  = (idx & 31)*8;
        int gr = row_base + row; if (gr >= NN) gr = NN-1;
        f16x8 v = __builtin_nontemporal_load((const f16x8*)&xg[(size_t)gr*KX + sg]);
        *(f16x8*)&x2l[row*X2P + sg] = v;
      }
    }
    __syncthreads();

    f32x4 acc[4][4] = {};   // [mi][0=r,1=z,2=n_x,3=n_h]

    // x2 part, K = 256 (A from LDS)
    #pragma unroll
    for (int k0 = 0; k0 < KX; k0 += 32){
      f16x8 a[4], b[3];
      #pragma unroll
      for (int mi = 0; mi < 4; ++mi) a[mi] = *(const f16x8*)&x2l[lrow[mi]*X2P + k0 + lk8];
      #pragma unroll
      for (int g = 0; g < 3; ++g) b[g] = *(const f16x8*)(Wih + bxo[g] + k0);
      #pragma unroll
      for (int mi = 0; mi < 4; ++mi){
        acc[mi][0] = __builtin_amdgcn_mfma_f32_16x16x32_f16(a[mi], b[0], acc[mi][0], 0,0,0);
        acc[mi][1] = __builtin_amdgcn_mfma_f32_16x16x32_f16(a[mi], b[1], acc[mi][1], 0,0,0);
        acc[mi][2] = __builtin_amdgcn_mfma_f32_16x16x32_f16(a[mi], b[2], acc[mi][2], 0,0,0);
      }
    }
    // h part, K = 128 (A from LDS)
    #pragma unroll
    for (int k0 = 0; k0 < H; k0 += 32){
      f16x8 a[4], b[3];
      #pragma unroll
      for (int mi = 0; mi < 4; ++mi) a[mi] = *(const f16x8*)&hl[lrow[mi]*LP + k0 + lk8];
      #pragma unroll
      for (int g = 0; g < 3; ++g) b[g] = *(const f16x8*)(Whh + bho[g] + k0);
      #pragma unroll
      for (int mi = 0; mi < 4; ++mi){
        acc[mi][0] = __builtin_amdgcn_mfma_f32_16x16x32_f16(a[mi], b[0], acc[mi][0], 0,0,0);
        acc[mi][1] = __builtin_amdgcn_mfma_f32_16x16x32_f16(a[mi], b[1], acc[mi][1], 0,0,0);
        acc[mi][3] = __builtin_amdgcn_mfma_f32_16x16x32_f16(a[mi], b[2], acc[mi][3], 0,0,0);
      }
    }
    __syncthreads();
    #pragma unroll
    for (int mi = 0; mi < 4; ++mi){
      #pragma unroll
      for (int rr = 0; rr < 4; ++rr){
        const int rl = mi*16 + r0 + rr;
        const int growu = row_base + rl;
        const float rg = sigmoidf_(acc[mi][0][rr] + bR);
        const float zg = sigmoidf_(acc[mi][1][rr] + bZ);
        const float ng = tanhf(acc[mi][2][rr] + bNi + rg*(acc[mi][3][rr] + bNh));
        const float hv = (1.0f - zg)*ng + zg*hst[mi][rr];
        hst[mi][rr] = hv;
        hl[rl*LP + col] = (f16)hv;
        if (t == TT-1 && growu < NN)
          h2fin[(size_t)growu*H + col] = hv;
      }
    }
    __syncthreads();
    gg.sync();   // phase-lock
  }
}

// ---------------- batched graph conv: 8 nodes/block, XCD-pinned t-slices ----------------
__global__ __launch_bounds__(512) void conv1_kernel(
    const f16* __restrict__ hall, const int2* __restrict__ pe,
    const int* __restrict__ off, const float* __restrict__ dis,
    const float* __restrict__ bias, f16* __restrict__ outall)
{
  const int b   = blockIdx.x;
  const int xcd = b & 7;
  const int v   = b >> 3;            // 0..3749
  const int tq  = v / 1250;          // 0..2
  const int t   = xcd + 8*tq;
  const int i   = (v - tq*1250)*8 + (threadIdx.x >> 6);
  const int f   = threadIdx.x & 63;  // f16x4 index
  const f16x4* hp = (const f16x4*)(hall + (size_t)t*NN*H1C);
  const float d = dis[i];
  const f16x4 sv = hp[(size_t)i*64 + f];
  float a0 = d*d*(float)sv[0];
  float a1 = d*d*(float)sv[1];
  float a2 = d*d*(float)sv[2];
  float a3 = d*d*(float)sv[3];
  int e = off[i]; const int e2 = off[i+1];
  const i32x2* pev = (const i32x2*)pe;
  for (; e + 8 <= e2; e += 8){
    i32x2 q[8];
    #pragma unroll
    for (int u = 0; u < 8; ++u) q[u] = __builtin_nontemporal_load(&pev[e+u]);
    #pragma unroll
    for (int u = 0; u < 8; ++u){
      const float wq = __int_as_float(q[u][1]);
      const f16x4 vv = hp[(size_t)q[u][0]*64 + f];
      a0 += wq*(float)vv[0]; a1 += wq*(float)vv[1];
      a2 += wq*(float)vv[2]; a3 += wq*(float)vv[3];
    }
  }
  for (; e < e2; ++e){
    const int2 q = pe[e];
    const float wq = __int_as_float(q.y);
    const f16x4 vv = hp[(size_t)q.x*64 + f];
    a0 += wq*(float)vv[0]; a1 += wq*(float)vv[1];
    a2 += wq*(float)vv[2]; a3 += wq*(float)vv[3];
  }
  const float4 bb = ((const float4*)bias)[f];
  a0 = fmaxf(a0 + bb.x, 0.0f);
  a1 = fmaxf(a1 + bb.y, 0.0f);
  a2 = fmaxf(a2 + bb.z, 0.0f);
  a3 = fmaxf(a3 + bb.w, 0.0f);
  f16x4 o; o[0]=(f16)a0; o[1]=(f16)a1; o[2]=(f16)a2; o[3]=(f16)a3;
  __builtin_nontemporal_store(o, (f16x4*)(outall + (size_t)t*NN*H1C) + (size_t)i*64 + f);
}

// conv2: H=128, single t, fp32 in/out
__global__ __launch_bounds__(64) void conv2_kernel(
    const float* __restrict__ h, const int2* __restrict__ pe,
    const int* __restrict__ off, const float* __restrict__ dis,
    const float* __restrict__ bias, float* __restrict__ out)
{
  const int i = blockIdx.x;
  const int f = threadIdx.x;            // float2 index
  const float2* hp = (const float2*)h;
  const float d = dis[i];
  const float2 sv = hp[(size_t)i*64 + f];
  float a0 = d*d*sv.x;
  float a1 = d*d*sv.y;
  int e = off[i]; const int e2 = off[i+1];
  for (; e + 4 <= e2; e += 4){
    int2 q[4];
    #pragma unroll
    for (int u = 0; u < 4; ++u) q[u] = pe[e+u];
    #pragma unroll
    for (int u = 0; u < 4; ++u){
      const float wq = __int_as_float(q[u].y);
      const float2 vv = hp[(size_t)q[u].x*64 + f];
      a0 += wq*vv.x; a1 += wq*vv.y;
    }
  }
  for (; e < e2; ++e){
    const int2 q = pe[e];
    const float wq = __int_as_float(q.y);
    const float2 vv = hp[(size_t)q.x*64 + f];
    a0 += wq*vv.x; a1 += wq*vv.y;
  }
  const float2 bb = ((const float2*)bias)[f];
  ((float2*)out)[(size_t)i*64 + f] = make_float2(a0 + bb.x, a1 + bb.y);
}

// ---------------- final dense + softmax ----------------
__global__ __launch_bounds__(256) void dense_kernel(const float* __restrict__ flat,
    const float* __restrict__ linW, float* __restrict__ logits)
{
  const int j   = blockIdx.x;
  const int tid = threadIdx.x;
  const int Q4  = FLATSZ/4;                  // 320000
  const int CH4 = Q4/64;                     // 5000 (gridDim.y == 64)
  const int s4  = blockIdx.y*CH4;
  const int e4  = s4 + CH4;
  const f32x4* w4 = (const f32x4*)&linW[(size_t)j*FLATSZ];
  const float4* f4 = (const float4*)flat;
  float part = 0.0f;
  for (int i = s4 + tid; i < e4; i += 256){
    const f32x4 a = __builtin_nontemporal_load(&w4[i]);
    const float4 b = f4[i];
    part += a[0]*b.x + a[1]*b.y + a[2]*b.z + a[3]*b.w;
  }
  __shared__ float red[256];
  red[tid] = part; __syncthreads();
  for (int s = 128; s > 0; s >>= 1){
    if (tid < s) red[tid] += red[tid + s];
    __syncthreads();
  }
  if (tid == 0) atomicAdd(&logits[j], red[0]);
}

__global__ __launch_bounds__(128) void softmax_kernel(const float* __restrict__ logits,
    const float* __restrict__ linb, float* __restrict__ out)
{
  __shared__ float red[128];
  const int tid = threadIdx.x;
  const float v = (tid < OUTD) ? logits[tid] + linb[tid] : -INFINITY;
  red[tid] = v; __syncthreads();
  for (int s = 64; s > 0; s >>= 1){
    if (tid < s) red[tid] = fmaxf(red[tid], red[tid + s]);
    __syncthreads();
  }
  const float mx = red[0]; __syncthreads();
  const float e = (tid < OUTD) ? expf(v - mx) : 0.0f;
  red[tid] = e; __syncthreads();
  for (int s = 64; s > 0; s >>= 1){
    if (tid < s) red[tid] += red[tid + s];
    __syncthreads();
  }
  const float inv = 1.0f/red[0];
  if (tid < OUTD) out[tid] = e*inv;
}

// ---------------- launch ----------------

extern "C" void kernel_launch(void* const* d_in, const int* in_sizes, int n_in,
                              void* d_out, int out_size, void* d_ws, size_t ws_size,
                              hipStream_t stream)
{
  const float* x     = (const float*)d_in[0];
  const int*   ei    = (const int*)  d_in[1];
  const float* W_ih1 = (const float*)d_in[2];
  const float* W_hh1 = (const float*)d_in[3];
  const float* b_ih1 = (const float*)d_in[4];
  const float* b_hh1 = (const float*)d_in[5];
  const float* bias1 = (const float*)d_in[6];
  const float* W_ih2 = (const float*)d_in[7];
  const float* W_hh2 = (const float*)d_in[8];
  const float* b_ih2 = (const float*)d_in[9];
  const float* b_hh2 = (const float*)d_in[10];
  const float* bias2 = (const float*)d_in[11];
  const float* lin_W = (const float*)d_in[12];
  const float* lin_b = (const float*)d_in[13];
  float* out = (float*)d_out;
  const int E = in_sizes[1]/2;
  (void)n_in; (void)out_size; (void)ws_size;

  char* p = (char*)d_ws;
  auto alloc = [&](size_t bytes)->void* {
    void* r = (void*)p;
    p += (bytes + 255) & ~(size_t)255;
    return r;
  };
  int*   cnt    = (int*)  alloc((size_t)NN*4);
  int*   cursor = (int*)  alloc((size_t)NN*4);
  int*   offs   = (int*)  alloc((size_t)(NN+1)*4);
  float* dis    = (float*)alloc((size_t)NN*4);
  int2*  pe     = (int2*) alloc((size_t)E*8);
  f16*   h1all  = (f16*)  alloc((size_t)TT*NN*H1C*2);   // 123 MB
  f16*   x2all  = (f16*)  alloc((size_t)TT*NN*H1C*2);   // 123 MB
  float* h2fin  = (float*)alloc((size_t)NN*H2C*4);
  float* out2   = (float*)alloc((size_t)NN*H2C*4);
  f16*   wih1h  = (f16*)  alloc((size_t)3*H1C*DIN*2);
  f16*   whh1h  = (f16*)  alloc((size_t)3*H1C*H1C*2);
  f16*   wih2h  = (f16*)  alloc((size_t)3*H2C*H1C*2);
  f16*   whh2h  = (f16*)  alloc((size_t)3*H2C*H2C*2);
  float* logits = (float*)alloc((size_t)OUTD*4);

  // ---- graph preprocessing ----
  init_kernel   <<<(NN+255)/256, 256, 0, stream>>>(cnt, cursor, logits, NN);
  count_kernel  <<<(E+255)/256, 256, 0, stream>>>(ei, cnt, E);
  dis_kernel    <<<(NN+255)/256, 256, 0, stream>>>(cnt, dis, NN);
  scan_kernel   <<<1, 256, 0, stream>>>(cnt, offs, NN);
  scatter_kernel<<<(E+255)/256, 256, 0, stream>>>(ei, dis, offs, cursor, pe, E);

  // ---- f16 weight casts ----
  cast_f16_kernel<<<((3*H1C*DIN/4)+255)/256, 256, 0, stream>>>((const float4*)W_ih1, (f16x4*)wih1h, 3*H1C*DIN/4);
  cast_f16_kernel<<<((3*H1C*H1C/4)+255)/256, 256, 0, stream>>>((const float4*)W_hh1, (f16x4*)whh1h, 3*H1C*H1C/4);
  cast_f16_kernel<<<((3*H2C*H1C/4)+255)/256, 256, 0, stream>>>((const float4*)W_ih2, (f16x4*)wih2h, 3*H2C*H1C/4);
  cast_f16_kernel<<<((3*H2C*H2C/4)+255)/256, 256, 0, stream>>>((const float4*)W_hh2, (f16x4*)whh2h, 3*H2C*H2C/4);

  const int CB = (NN + 63)/64;   // 157

  // ---- layer-1 chain (cooperative, phase-locked) ----
  {
    void* a1[] = { (void*)&x, (void*)&wih1h, (void*)&whh1h, (void*)&b_ih1,
                   (void*)&b_hh1, (void*)&h1all };
    hipLaunchCooperativeKernel((const void*)gru1_chain_kernel,
                               dim3(CB), dim3(512), a1, 0, stream);
  }

  // ---- batched conv1 (XCD-pinned, 8 nodes/block) ----
  conv1_kernel<<<24*NN/8, 512, 0, stream>>>(h1all, pe, offs, dis, bias1, x2all);

  // ---- layer-2 chain (cooperative, phase-locked) ----
  {
    void* a2[] = { (void*)&x2all, (void*)&wih2h, (void*)&whh2h, (void*)&b_ih2,
                   (void*)&b_hh2, (void*)&h2fin };
    hipLaunchCooperativeKernel((const void*)gru2_chain_kernel,
                               dim3(CB), dim3(512), a2, 0, stream);
  }

  conv2_kernel<<<NN, 64, 0, stream>>>(h2fin, pe, offs, dis, bias2, out2);
  dense_kernel<<<dim3(OUTD, 64), 256, 0, stream>>>(out2, lin_W, logits);
  softmax_kernel<<<1, 128, 0, stream>>>(logits, lin_b, out);
}

// Round 15
// 1901.329 us; speedup vs baseline: 1.3860x; 1.3860x over previous
//
#include <hip/hip_runtime.h>
#include <math.h>

#define TT   24
#define NN   10000
#define DIN  128
#define H1C  256
#define H2C  128
#define OUTD 100
#define FLATSZ (NN*H2C)

typedef _Float16 f16;
typedef _Float16 f16x4 __attribute__((ext_vector_type(4)));
typedef _Float16 f16x8 __attribute__((ext_vector_type(8)));
typedef float    f32x4 __attribute__((ext_vector_type(4)));
typedef int      i32x2 __attribute__((ext_vector_type(2)));

__device__ __forceinline__ float sigmoidf_(float x){ return 1.0f/(1.0f+expf(-x)); }

// ---------------- small utility kernels ----------------

__global__ __launch_bounds__(256) void cast_f16_kernel(const float4* __restrict__ in,
                                                       f16x4* __restrict__ out, int n4){
  int i = blockIdx.x*256 + threadIdx.x;
  if (i < n4){
    float4 v = in[i];
    f16x4 o; o[0]=(f16)v.x; o[1]=(f16)v.y; o[2]=(f16)v.z; o[3]=(f16)v.w;
    out[i] = o;
  }
}

__global__ __launch_bounds__(256) void init_kernel(int* __restrict__ cnt, int* __restrict__ cursor,
                                                   float* __restrict__ logits, int n){
  int i = blockIdx.x*256 + threadIdx.x;
  if (i < n){ cnt[i] = 0; cursor[i] = 0; }
  if (i < OUTD) logits[i] = 0.0f;
}

__global__ __launch_bounds__(256) void count_kernel(const int* __restrict__ ei, int* __restrict__ cnt, int E){
  int e = blockIdx.x*256 + threadIdx.x;
  if (e < E) atomicAdd(&cnt[ei[E + e]], 1);
}

__global__ __launch_bounds__(256) void dis_kernel(const int* __restrict__ cnt, float* __restrict__ dis, int n){
  int i = blockIdx.x*256 + threadIdx.x;
  if (i < n) dis[i] = rsqrtf((float)(cnt[i] + 1));   // +1 self-loop
}

__global__ __launch_bounds__(256) void scan_kernel(const int* __restrict__ cnt, int* __restrict__ off, int n){
  __shared__ int sums[256];
  const int tid = threadIdx.x;
  const int CH  = 40;
  const int base = tid*CH;
  int s = 0;
  for (int i = 0; i < CH; ++i){ int idx = base + i; if (idx < n) s += cnt[idx]; }
  sums[tid] = s; __syncthreads();
  for (int d = 1; d < 256; d <<= 1){
    int v = (tid >= d) ? sums[tid - d] : 0;
    __syncthreads();
    sums[tid] += v;
    __syncthreads();
  }
  int run = (tid == 0) ? 0 : sums[tid - 1];
  for (int i = 0; i < CH; ++i){
    int idx = base + i;
    if (idx < n){ off[idx] = run; run += cnt[idx]; }
  }
  if (tid == 0) off[n] = sums[255];
}

__global__ __launch_bounds__(256) void scatter_kernel(const int* __restrict__ ei, const float* __restrict__ dis,
                                                      const int* __restrict__ off, int* __restrict__ cursor,
                                                      int2* __restrict__ pe, int E){
  int e = blockIdx.x*256 + threadIdx.x;
  if (e < E){
    int r = ei[e];
    int c = ei[E + e];
    int pos = off[c] + atomicAdd(&cursor[c], 1);
    pe[pos] = make_int2(r, __float_as_int(dis[r]*dis[c]));
  }
}

// ---------------- layer-1 GRU chain: 64 rows/block, 1024 thr = 16 col-groups x 16 cols ----------------
// Weights read ONCE per block-step (col groups partition 256 cols). acc = 64 f32/thread (no spill).
// 4 waves/SIMD resident (2x R11's latency hiding), same weight traffic.
__global__ __launch_bounds__(1024, 4) void gru1_chain_kernel(
    const float* __restrict__ x, const f16* __restrict__ Wih,
    const f16* __restrict__ Whh, const float* __restrict__ bih,
    const float* __restrict__ bhh, f16* __restrict__ h1all)
{
  constexpr int H  = H1C;      // 256
  constexpr int LP = H + 8;    // 264 f16 pitch (hl)
  constexpr int XP = DIN + 8;  // 136 f16 pitch (xl)
  __shared__ __align__(16) f16 hl[64*LP];   // 33.8 KB
  __shared__ __align__(16) f16 xl[64*XP];   // 17.4 KB

  const int tid  = threadIdx.x;
  const int lane = tid & 63;
  const int w    = tid >> 6;        // 0..15 col group (16 cols each)
  const int lr   = lane & 15;
  const int lk8  = (lane >> 4)*8;
  const int r0   = (lane >> 4)*4;
  const int row_base = blockIdx.x*64;

  for (int k = tid*8; k < 64*LP; k += 1024*8)
    *(f16x8*)&hl[k] = (f16x8){0,0,0,0,0,0,0,0};

  int lrow[4];
  #pragma unroll
  for (int mi = 0; mi < 4; ++mi) lrow[mi] = mi*16 + lr;

  const int col = w*16 + lr;
  int bxo[3], bho[3];
  #pragma unroll
  for (int g = 0; g < 3; ++g){
    bxo[g] = (g*H + col)*DIN + lk8;
    bho[g] = (g*H + col)*H   + lk8;
  }
  const float bR  = bih[col]       + bhh[col];
  const float bZ  = bih[H+col]     + bhh[H+col];
  const float bNi = bih[2*H+col];
  const float bNh = bhh[2*H+col];

  float hst[4][4] = {};   // [mi][rr] fp32 state, thread-owned across t
  __syncthreads();

  for (int t = 0; t < TT; ++t){
    // ---- stage x tile (64 rows x 128 f32 -> f16), nt loads; 2048 chunks / 1024 thr ----
    {
      const float* xg = x + (size_t)t*NN*DIN;
      #pragma unroll
      for (int s = 0; s < 2; ++s){
        const int idx = s*1024 + tid;      // 0..2047
        const int row = idx >> 5;
        const int c4  = (idx & 31)*4;
        int gr = row_base + row; if (gr >= NN) gr = NN-1;
        const f32x4 v = __builtin_nontemporal_load((const f32x4*)&xg[(size_t)gr*DIN + c4]);
        f16x4 o; o[0]=(f16)v[0]; o[1]=(f16)v[1]; o[2]=(f16)v[2]; o[3]=(f16)v[3];
        *(f16x4*)&xl[row*XP + c4] = o;
      }
    }
    __syncthreads();   // xl ready; hl stable

    f32x4 acc[4][4] = {};   // [mi][0=r,1=z,2=n_x,3=n_h]

    // x part, K = 128 (A from LDS)
    #pragma unroll
    for (int k0 = 0; k0 < DIN; k0 += 32){
      f16x8 a[4], b[3];
      #pragma unroll
      for (int mi = 0; mi < 4; ++mi) a[mi] = *(const f16x8*)&xl[lrow[mi]*XP + k0 + lk8];
      #pragma unroll
      for (int g = 0; g < 3; ++g) b[g] = *(const f16x8*)(Wih + bxo[g] + k0);
      #pragma unroll
      for (int mi = 0; mi < 4; ++mi){
        acc[mi][0] = __builtin_amdgcn_mfma_f32_16x16x32_f16(a[mi], b[0], acc[mi][0], 0,0,0);
        acc[mi][1] = __builtin_amdgcn_mfma_f32_16x16x32_f16(a[mi], b[1], acc[mi][1], 0,0,0);
        acc[mi][2] = __builtin_amdgcn_mfma_f32_16x16x32_f16(a[mi], b[2], acc[mi][2], 0,0,0);
      }
    }
    // h part, K = 256 (A from LDS)
    #pragma unroll
    for (int k0 = 0; k0 < H; k0 += 32){
      f16x8 a[4], b[3];
      #pragma unroll
      for (int mi = 0; mi < 4; ++mi) a[mi] = *(const f16x8*)&hl[lrow[mi]*LP + k0 + lk8];
      #pragma unroll
      for (int g = 0; g < 3; ++g) b[g] = *(const f16x8*)(Whh + bho[g] + k0);
      #pragma unroll
      for (int mi = 0; mi < 4; ++mi){
        acc[mi][0] = __builtin_amdgcn_mfma_f32_16x16x32_f16(a[mi], b[0], acc[mi][0], 0,0,0);
        acc[mi][1] = __builtin_amdgcn_mfma_f32_16x16x32_f16(a[mi], b[1], acc[mi][1], 0,0,0);
        acc[mi][3] = __builtin_amdgcn_mfma_f32_16x16x32_f16(a[mi], b[2], acc[mi][3], 0,0,0);
      }
    }
    __syncthreads();   // all reads of hl/xl done
    // epilogue: gates + register state + hl update
    #pragma unroll
    for (int mi = 0; mi < 4; ++mi){
      #pragma unroll
      for (int rr = 0; rr < 4; ++rr){
        const int rl = mi*16 + r0 + rr;
        const float rg = sigmoidf_(acc[mi][0][rr] + bR);
        const float zg = sigmoidf_(acc[mi][1][rr] + bZ);
        const float ng = tanhf(acc[mi][2][rr] + bNi + rg*(acc[mi][3][rr] + bNh));
        const float hv = (1.0f - zg)*ng + zg*hst[mi][rr];
        hst[mi][rr] = hv;
        hl[rl*LP + col] = (f16)hv;
      }
    }
    __syncthreads();   // hl updated
    // coalesced nt copy LDS -> h1all[t]; 2048 chunks / 1024 thr
    f16* ho = h1all + ((size_t)t*NN + row_base)*H;
    #pragma unroll
    for (int c = 0; c < 2; ++c){
      const int idx = c*1024 + tid;        // 0..2047
      const int row = idx >> 5, seg = idx & 31;
      if (row_base + row < NN)
        __builtin_nontemporal_store(*(const f16x8*)&hl[row*LP + seg*8],
                                    (f16x8*)&ho[(size_t)row*H + seg*8]);
    }
  }
}

// ---------------- layer-2 GRU chain: 64 rows/block, 1024 thr = 2 rowg x 8 colg x 16 cols ----------------
__global__ __launch_bounds__(1024, 4) void gru2_chain_kernel(
    const f16* __restrict__ x2all, const f16* __restrict__ Wih,
    const f16* __restrict__ Whh, const float* __restrict__ bih,
    const float* __restrict__ bhh, float* __restrict__ h2fin)
{
  constexpr int H   = H2C;     // 128
  constexpr int KX  = H1C;     // 256
  constexpr int LP  = H + 8;   // 136
  constexpr int X2P = KX + 8;  // 264
  __shared__ __align__(16) f16 hl[64*LP];    // 17.4 KB
  __shared__ __align__(16) f16 x2l[64*X2P];  // 33.8 KB

  const int tid  = threadIdx.x;
  const int lane = tid & 63;
  const int w    = tid >> 6;        // 0..15
  const int wm   = w >> 3;          // 0..1 row group (32 rows)
  const int wc   = w & 7;           // 0..7 col group (16 cols)
  const int lr   = lane & 15;
  const int lk8  = (lane >> 4)*8;
  const int r0   = (lane >> 4)*4;
  const int row_base = blockIdx.x*64;

  for (int k = tid*8; k < 64*LP; k += 1024*8)
    *(f16x8*)&hl[k] = (f16x8){0,0,0,0,0,0,0,0};

  int lrow[2];
  #pragma unroll
  for (int mi = 0; mi < 2; ++mi) lrow[mi] = wm*32 + mi*16 + lr;

  const int col = wc*16 + lr;
  int bxo[3], bho[3];
  #pragma unroll
  for (int g = 0; g < 3; ++g){
    bxo[g] = (g*H + col)*KX + lk8;
    bho[g] = (g*H + col)*H  + lk8;
  }
  const float bR  = bih[col]       + bhh[col];
  const float bZ  = bih[H+col]     + bhh[H+col];
  const float bNi = bih[2*H+col];
  const float bNh = bhh[2*H+col];

  float hst[2][4] = {};   // [mi][rr]
  __syncthreads();

  for (int t = 0; t < TT; ++t){
    // ---- stage x2 tile (64 rows x 256 f16), nt loads; 2048 chunks / 1024 thr ----
    {
      const f16* xg = x2all + (size_t)t*NN*KX;
      #pragma unroll
      for (int s = 0; s < 2; ++s){
        const int idx = s*1024 + tid;      // 0..2047
        const int row = idx >> 5;
        const int sg  = (idx & 31)*8;
        int gr = row_base + row; if (gr >= NN) gr = NN-1;
        f16x8 v = __builtin_nontemporal_load((const f16x8*)&xg[(size_t)gr*KX + sg]);
        *(f16x8*)&x2l[row*X2P + sg] = v;
      }
    }
    __syncthreads();

    f32x4 acc[2][4] = {};   // [mi][0=r,1=z,2=n_x,3=n_h]

    // x2 part, K = 256 (A from LDS)
    #pragma unroll
    for (int k0 = 0; k0 < KX; k0 += 32){
      f16x8 a[2], b[3];
      #pragma unroll
      for (int mi = 0; mi < 2; ++mi) a[mi] = *(const f16x8*)&x2l[lrow[mi]*X2P + k0 + lk8];
      #pragma unroll
      for (int g = 0; g < 3; ++g) b[g] = *(const f16x8*)(Wih + bxo[g] + k0);
      #pragma unroll
      for (int mi = 0; mi < 2; ++mi){
        acc[mi][0] = __builtin_amdgcn_mfma_f32_16x16x32_f16(a[mi], b[0], acc[mi][0], 0,0,0);
        acc[mi][1] = __builtin_amdgcn_mfma_f32_16x16x32_f16(a[mi], b[1], acc[mi][1], 0,0,0);
        acc[mi][2] = __builtin_amdgcn_mfma_f32_16x16x32_f16(a[mi], b[2], acc[mi][2], 0,0,0);
      }
    }
    // h part, K = 128 (A from LDS)
    #pragma unroll
    for (int k0 = 0; k0 < H; k0 += 32){
      f16x8 a[2], b[3];
      #pragma unroll
      for (int mi = 0; mi < 2; ++mi) a[mi] = *(const f16x8*)&hl[lrow[mi]*LP + k0 + lk8];
      #pragma unroll
      for (int g = 0; g < 3; ++g) b[g] = *(const f16x8*)(Whh + bho[g] + k0);
      #pragma unroll
      for (int mi = 0; mi < 2; ++mi){
        acc[mi][0] = __builtin_amdgcn_mfma_f32_16x16x32_f16(a[mi], b[0], acc[mi][0], 0,0,0);
        acc[mi][1] = __builtin_amdgcn_mfma_f32_16x16x32_f16(a[mi], b[1], acc[mi][1], 0,0,0);
        acc[mi][3] = __builtin_amdgcn_mfma_f32_16x16x32_f16(a[mi], b[2], acc[mi][3], 0,0,0);
      }
    }
    __syncthreads();
    #pragma unroll
    for (int mi = 0; mi < 2; ++mi){
      #pragma unroll
      for (int rr = 0; rr < 4; ++rr){
        const int rl = wm*32 + mi*16 + r0 + rr;
        const int growu = row_base + rl;
        const float rg = sigmoidf_(acc[mi][0][rr] + bR);
        const float zg = sigmoidf_(acc[mi][1][rr] + bZ);
        const float ng = tanhf(acc[mi][2][rr] + bNi + rg*(acc[mi][3][rr] + bNh));
        const float hv = (1.0f - zg)*ng + zg*hst[mi][rr];
        hst[mi][rr] = hv;
        hl[rl*LP + col] = (f16)hv;
        if (t == TT-1 && growu < NN)
          h2fin[(size_t)growu*H + col] = hv;
      }
    }
    __syncthreads();
  }
}

// ---------------- batched graph conv: 8 nodes/block, XCD-pinned t-slices ----------------
__global__ __launch_bounds__(512) void conv1_kernel(
    const f16* __restrict__ hall, const int2* __restrict__ pe,
    const int* __restrict__ off, const float* __restrict__ dis,
    const float* __restrict__ bias, f16* __restrict__ outall)
{
  const int b   = blockIdx.x;
  const int xcd = b & 7;
  const int v   = b >> 3;            // 0..3749
  const int tq  = v / 1250;          // 0..2
  const int t   = xcd + 8*tq;
  const int i   = (v - tq*1250)*8 + (threadIdx.x >> 6);
  const int f   = threadIdx.x & 63;  // f16x4 index
  const f16x4* hp = (const f16x4*)(hall + (size_t)t*NN*H1C);
  const float d = dis[i];
  const f16x4 sv = hp[(size_t)i*64 + f];
  float a0 = d*d*(float)sv[0];
  float a1 = d*d*(float)sv[1];
  float a2 = d*d*(float)sv[2];
  float a3 = d*d*(float)sv[3];
  int e = off[i]; const int e2 = off[i+1];
  const i32x2* pev = (const i32x2*)pe;
  for (; e + 8 <= e2; e += 8){
    i32x2 q[8];
    #pragma unroll
    for (int u = 0; u < 8; ++u) q[u] = __builtin_nontemporal_load(&pev[e+u]);
    #pragma unroll
    for (int u = 0; u < 8; ++u){
      const float wq = __int_as_float(q[u][1]);
      const f16x4 vv = hp[(size_t)q[u][0]*64 + f];
      a0 += wq*(float)vv[0]; a1 += wq*(float)vv[1];
      a2 += wq*(float)vv[2]; a3 += wq*(float)vv[3];
    }
  }
  for (; e < e2; ++e){
    const int2 q = pe[e];
    const float wq = __int_as_float(q.y);
    const f16x4 vv = hp[(size_t)q.x*64 + f];
    a0 += wq*(float)vv[0]; a1 += wq*(float)vv[1];
    a2 += wq*(float)vv[2]; a3 += wq*(float)vv[3];
  }
  const float4 bb = ((const float4*)bias)[f];
  a0 = fmaxf(a0 + bb.x, 0.0f);
  a1 = fmaxf(a1 + bb.y, 0.0f);
  a2 = fmaxf(a2 + bb.z, 0.0f);
  a3 = fmaxf(a3 + bb.w, 0.0f);
  f16x4 o; o[0]=(f16)a0; o[1]=(f16)a1; o[2]=(f16)a2; o[3]=(f16)a3;
  __builtin_nontemporal_store(o, (f16x4*)(outall + (size_t)t*NN*H1C) + (size_t)i*64 + f);
}

// conv2: H=128, single t, fp32 in/out
__global__ __launch_bounds__(64) void conv2_kernel(
    const float* __restrict__ h, const int2* __restrict__ pe,
    const int* __restrict__ off, const float* __restrict__ dis,
    const float* __restrict__ bias, float* __restrict__ out)
{
  const int i = blockIdx.x;
  const int f = threadIdx.x;            // float2 index
  const float2* hp = (const float2*)h;
  const float d = dis[i];
  const float2 sv = hp[(size_t)i*64 + f];
  float a0 = d*d*sv.x;
  float a1 = d*d*sv.y;
  int e = off[i]; const int e2 = off[i+1];
  for (; e + 4 <= e2; e += 4){
    int2 q[4];
    #pragma unroll
    for (int u = 0; u < 4; ++u) q[u] = pe[e+u];
    #pragma unroll
    for (int u = 0; u < 4; ++u){
      const float wq = __int_as_float(q[u].y);
      const float2 vv = hp[(size_t)q[u].x*64 + f];
      a0 += wq*vv.x; a1 += wq*vv.y;
    }
  }
  for (; e < e2; ++e){
    const int2 q = pe[e];
    const float wq = __int_as_float(q.y);
    const float2 vv = hp[(size_t)q.x*64 + f];
    a0 += wq*vv.x; a1 += wq*vv.y;
  }
  const float2 bb = ((const float2*)bias)[f];
  ((float2*)out)[(size_t)i*64 + f] = make_float2(a0 + bb.x, a1 + bb.y);
}

// ---------------- final dense + softmax ----------------
__global__ __launch_bounds__(256) void dense_kernel(const float* __restrict__ flat,
    const float* __restrict__ linW, float* __restrict__ logits)
{
  const int j   = blockIdx.x;
  const int tid = threadIdx.x;
  const int Q4  = FLATSZ/4;                  // 320000
  const int CH4 = Q4/64;                     // 5000 (gridDim.y == 64)
  const int s4  = blockIdx.y*CH4;
  const int e4  = s4 + CH4;
  const f32x4* w4 = (const f32x4*)&linW[(size_t)j*FLATSZ];
  const float4* f4 = (const float4*)flat;
  float part = 0.0f;
  for (int i = s4 + tid; i < e4; i += 256){
    const f32x4 a = __builtin_nontemporal_load(&w4[i]);
    const float4 b = f4[i];
    part += a[0]*b.x + a[1]*b.y + a[2]*b.z + a[3]*b.w;
  }
  __shared__ float red[256];
  red[tid] = part; __syncthreads();
  for (int s = 128; s > 0; s >>= 1){
    if (tid < s) red[tid] += red[tid + s];
    __syncthreads();
  }
  if (tid == 0) atomicAdd(&logits[j], red[0]);
}

__global__ __launch_bounds__(128) void softmax_kernel(const float* __restrict__ logits,
    const float* __restrict__ linb, float* __restrict__ out)
{
  __shared__ float red[128];
  const int tid = threadIdx.x;
  const float v = (tid < OUTD) ? logits[tid] + linb[tid] : -INFINITY;
  red[tid] = v; __syncthreads();
  for (int s = 64; s > 0; s >>= 1){
    if (tid < s) red[tid] = fmaxf(red[tid], red[tid + s]);
    __syncthreads();
  }
  const float mx = red[0]; __syncthreads();
  const float e = (tid < OUTD) ? expf(v - mx) : 0.0f;
  red[tid] = e; __syncthreads();
  for (int s = 64; s > 0; s >>= 1){
    if (tid < s) red[tid] += red[tid + s];
    __syncthreads();
  }
  const float inv = 1.0f/red[0];
  if (tid < OUTD) out[tid] = e*inv;
}

// ---------------- launch ----------------

extern "C" void kernel_launch(void* const* d_in, const int* in_sizes, int n_in,
                              void* d_out, int out_size, void* d_ws, size_t ws_size,
                              hipStream_t stream)
{
  const float* x     = (const float*)d_in[0];
  const int*   ei    = (const int*)  d_in[1];
  const float* W_ih1 = (const float*)d_in[2];
  const float* W_hh1 = (const float*)d_in[3];
  const float* b_ih1 = (const float*)d_in[4];
  const float* b_hh1 = (const float*)d_in[5];
  const float* bias1 = (const float*)d_in[6];
  const float* W_ih2 = (const float*)d_in[7];
  const float* W_hh2 = (const float*)d_in[8];
  const float* b_ih2 = (const float*)d_in[9];
  const float* b_hh2 = (const float*)d_in[10];
  const float* bias2 = (const float*)d_in[11];
  const float* lin_W = (const float*)d_in[12];
  const float* lin_b = (const float*)d_in[13];
  float* out = (float*)d_out;
  const int E = in_sizes[1]/2;
  (void)n_in; (void)out_size; (void)ws_size;

  char* p = (char*)d_ws;
  auto alloc = [&](size_t bytes)->void* {
    void* r = (void*)p;
    p += (bytes + 255) & ~(size_t)255;
    return r;
  };
  int*   cnt    = (int*)  alloc((size_t)NN*4);
  int*   cursor = (int*)  alloc((size_t)NN*4);
  int*   offs   = (int*)  alloc((size_t)(NN+1)*4);
  float* dis    = (float*)alloc((size_t)NN*4);
  int2*  pe     = (int2*) alloc((size_t)E*8);
  f16*   h1all  = (f16*)  alloc((size_t)TT*NN*H1C*2);   // 123 MB
  f16*   x2all  = (f16*)  alloc((size_t)TT*NN*H1C*2);   // 123 MB
  float* h2fin  = (float*)alloc((size_t)NN*H2C*4);
  float* out2   = (float*)alloc((size_t)NN*H2C*4);
  f16*   wih1h  = (f16*)  alloc((size_t)3*H1C*DIN*2);
  f16*   whh1h  = (f16*)  alloc((size_t)3*H1C*H1C*2);
  f16*   wih2h  = (f16*)  alloc((size_t)3*H2C*H1C*2);
  f16*   whh2h  = (f16*)  alloc((size_t)3*H2C*H2C*2);
  float* logits = (float*)alloc((size_t)OUTD*4);

  // ---- graph preprocessing ----
  init_kernel   <<<(NN+255)/256, 256, 0, stream>>>(cnt, cursor, logits, NN);
  count_kernel  <<<(E+255)/256, 256, 0, stream>>>(ei, cnt, E);
  dis_kernel    <<<(NN+255)/256, 256, 0, stream>>>(cnt, dis, NN);
  scan_kernel   <<<1, 256, 0, stream>>>(cnt, offs, NN);
  scatter_kernel<<<(E+255)/256, 256, 0, stream>>>(ei, dis, offs, cursor, pe, E);

  // ---- f16 weight casts ----
  cast_f16_kernel<<<((3*H1C*DIN/4)+255)/256, 256, 0, stream>>>((const float4*)W_ih1, (f16x4*)wih1h, 3*H1C*DIN/4);
  cast_f16_kernel<<<((3*H1C*H1C/4)+255)/256, 256, 0, stream>>>((const float4*)W_hh1, (f16x4*)whh1h, 3*H1C*H1C/4);
  cast_f16_kernel<<<((3*H2C*H1C/4)+255)/256, 256, 0, stream>>>((const float4*)W_ih2, (f16x4*)wih2h, 3*H2C*H1C/4);
  cast_f16_kernel<<<((3*H2C*H2C/4)+255)/256, 256, 0, stream>>>((const float4*)W_hh2, (f16x4*)whh2h, 3*H2C*H2C/4);

  const int CB = (NN + 63)/64;   // 157

  // ---- layer-1 chain ----
  gru1_chain_kernel<<<CB, 1024, 0, stream>>>(x, wih1h, whh1h, b_ih1, b_hh1, h1all);

  // ---- batched conv1 (XCD-pinned, 8 nodes/block) ----
  conv1_kernel<<<24*NN/8, 512, 0, stream>>>(h1all, pe, offs, dis, bias1, x2all);

  // ---- layer-2 chain ----
  gru2_chain_kernel<<<CB, 1024, 0, stream>>>(x2all, wih2h, whh2h, b_ih2, b_hh2, h2fin);

  conv2_kernel<<<NN, 64, 0, stream>>>(h2fin, pe, offs, dis, bias2, out2);
  dense_kernel<<<dim3(OUTD, 64), 256, 0, stream>>>(out2, lin_W, logits);
  softmax_kernel<<<1, 128, 0, stream>>>(logits, lin_b, out);
}

// Round 16
// 1722.899 us; speedup vs baseline: 1.5295x; 1.1036x over previous
//
#include <hip/hip_runtime.h>
#include <math.h>

#define TT   24
#define NN   10000
#define DIN  128
#define H1C  256
#define H2C  128
#define OUTD 100
#define FLATSZ (NN*H2C)

typedef _Float16 f16;
typedef _Float16 f16x4 __attribute__((ext_vector_type(4)));
typedef _Float16 f16x8 __attribute__((ext_vector_type(8)));
typedef float    f32x4 __attribute__((ext_vector_type(4)));
typedef int      i32x2 __attribute__((ext_vector_type(2)));

__device__ __forceinline__ float sigmoidf_(float x){ return 1.0f/(1.0f+expf(-x)); }

// ---------------- small utility kernels ----------------

__global__ __launch_bounds__(256) void cast_f16_kernel(const float4* __restrict__ in,
                                                       f16x4* __restrict__ out, int n4){
  int i = blockIdx.x*256 + threadIdx.x;
  if (i < n4){
    float4 v = in[i];
    f16x4 o; o[0]=(f16)v.x; o[1]=(f16)v.y; o[2]=(f16)v.z; o[3]=(f16)v.w;
    out[i] = o;
  }
}

__global__ __launch_bounds__(256) void init_kernel(int* __restrict__ cnt, int* __restrict__ cursor,
                                                   float* __restrict__ logits, int n){
  int i = blockIdx.x*256 + threadIdx.x;
  if (i < n){ cnt[i] = 0; cursor[i] = 0; }
  if (i < OUTD) logits[i] = 0.0f;
}

__global__ __launch_bounds__(256) void count_kernel(const int* __restrict__ ei, int* __restrict__ cnt, int E){
  int e = blockIdx.x*256 + threadIdx.x;
  if (e < E) atomicAdd(&cnt[ei[E + e]], 1);
}

__global__ __launch_bounds__(256) void dis_kernel(const int* __restrict__ cnt, float* __restrict__ dis, int n){
  int i = blockIdx.x*256 + threadIdx.x;
  if (i < n) dis[i] = rsqrtf((float)(cnt[i] + 1));   // +1 self-loop
}

__global__ __launch_bounds__(256) void scan_kernel(const int* __restrict__ cnt, int* __restrict__ off, int n){
  __shared__ int sums[256];
  const int tid = threadIdx.x;
  const int CH  = 40;
  const int base = tid*CH;
  int s = 0;
  for (int i = 0; i < CH; ++i){ int idx = base + i; if (idx < n) s += cnt[idx]; }
  sums[tid] = s; __syncthreads();
  for (int d = 1; d < 256; d <<= 1){
    int v = (tid >= d) ? sums[tid - d] : 0;
    __syncthreads();
    sums[tid] += v;
    __syncthreads();
  }
  int run = (tid == 0) ? 0 : sums[tid - 1];
  for (int i = 0; i < CH; ++i){
    int idx = base + i;
    if (idx < n){ off[idx] = run; run += cnt[idx]; }
  }
  if (tid == 0) off[n] = sums[255];
}

__global__ __launch_bounds__(256) void scatter_kernel(const int* __restrict__ ei, const float* __restrict__ dis,
                                                      const int* __restrict__ off, int* __restrict__ cursor,
                                                      int2* __restrict__ pe, int E){
  int e = blockIdx.x*256 + threadIdx.x;
  if (e < E){
    int r = ei[e];
    int c = ei[E + e];
    int pos = off[c] + atomicAdd(&cursor[c], 1);
    pe[pos] = make_int2(r, __float_as_int(dis[r]*dis[c]));
  }
}

// ---------------- layer-1 GRU chain: 64 rows/block, 1024 thr = 16 col-groups x 16 cols ----------------
// (R15-measured: 845 us, no spill.) Weights read once per block-step; 4 waves/SIMD.
__global__ __launch_bounds__(1024, 4) void gru1_chain_kernel(
    const float* __restrict__ x, const f16* __restrict__ Wih,
    const f16* __restrict__ Whh, const float* __restrict__ bih,
    const float* __restrict__ bhh, f16* __restrict__ h1all)
{
  constexpr int H  = H1C;      // 256
  constexpr int LP = H + 8;    // 264 f16 pitch (hl)
  constexpr int XP = DIN + 8;  // 136 f16 pitch (xl)
  __shared__ __align__(16) f16 hl[64*LP];   // 33.8 KB
  __shared__ __align__(16) f16 xl[64*XP];   // 17.4 KB

  const int tid  = threadIdx.x;
  const int lane = tid & 63;
  const int w    = tid >> 6;        // 0..15 col group (16 cols each)
  const int lr   = lane & 15;
  const int lk8  = (lane >> 4)*8;
  const int r0   = (lane >> 4)*4;
  const int row_base = blockIdx.x*64;

  for (int k = tid*8; k < 64*LP; k += 1024*8)
    *(f16x8*)&hl[k] = (f16x8){0,0,0,0,0,0,0,0};

  int lrow[4];
  #pragma unroll
  for (int mi = 0; mi < 4; ++mi) lrow[mi] = mi*16 + lr;

  const int col = w*16 + lr;
  int bxo[3], bho[3];
  #pragma unroll
  for (int g = 0; g < 3; ++g){
    bxo[g] = (g*H + col)*DIN + lk8;
    bho[g] = (g*H + col)*H   + lk8;
  }
  const float bR  = bih[col]       + bhh[col];
  const float bZ  = bih[H+col]     + bhh[H+col];
  const float bNi = bih[2*H+col];
  const float bNh = bhh[2*H+col];

  float hst[4][4] = {};   // [mi][rr] fp32 state, thread-owned across t
  __syncthreads();

  for (int t = 0; t < TT; ++t){
    // ---- stage x tile (64 rows x 128 f32 -> f16), nt loads ----
    {
      const float* xg = x + (size_t)t*NN*DIN;
      #pragma unroll
      for (int s = 0; s < 2; ++s){
        const int idx = s*1024 + tid;      // 0..2047
        const int row = idx >> 5;
        const int c4  = (idx & 31)*4;
        int gr = row_base + row; if (gr >= NN) gr = NN-1;
        const f32x4 v = __builtin_nontemporal_load((const f32x4*)&xg[(size_t)gr*DIN + c4]);
        f16x4 o; o[0]=(f16)v[0]; o[1]=(f16)v[1]; o[2]=(f16)v[2]; o[3]=(f16)v[3];
        *(f16x4*)&xl[row*XP + c4] = o;
      }
    }
    __syncthreads();   // xl ready; hl stable

    f32x4 acc[4][4] = {};   // [mi][0=r,1=z,2=n_x,3=n_h]

    // x part, K = 128 (A from LDS)
    #pragma unroll
    for (int k0 = 0; k0 < DIN; k0 += 32){
      f16x8 a[4], b[3];
      #pragma unroll
      for (int mi = 0; mi < 4; ++mi) a[mi] = *(const f16x8*)&xl[lrow[mi]*XP + k0 + lk8];
      #pragma unroll
      for (int g = 0; g < 3; ++g) b[g] = *(const f16x8*)(Wih + bxo[g] + k0);
      #pragma unroll
      for (int mi = 0; mi < 4; ++mi){
        acc[mi][0] = __builtin_amdgcn_mfma_f32_16x16x32_f16(a[mi], b[0], acc[mi][0], 0,0,0);
        acc[mi][1] = __builtin_amdgcn_mfma_f32_16x16x32_f16(a[mi], b[1], acc[mi][1], 0,0,0);
        acc[mi][2] = __builtin_amdgcn_mfma_f32_16x16x32_f16(a[mi], b[2], acc[mi][2], 0,0,0);
      }
    }
    // h part, K = 256 (A from LDS)
    #pragma unroll
    for (int k0 = 0; k0 < H; k0 += 32){
      f16x8 a[4], b[3];
      #pragma unroll
      for (int mi = 0; mi < 4; ++mi) a[mi] = *(const f16x8*)&hl[lrow[mi]*LP + k0 + lk8];
      #pragma unroll
      for (int g = 0; g < 3; ++g) b[g] = *(const f16x8*)(Whh + bho[g] + k0);
      #pragma unroll
      for (int mi = 0; mi < 4; ++mi){
        acc[mi][0] = __builtin_amdgcn_mfma_f32_16x16x32_f16(a[mi], b[0], acc[mi][0], 0,0,0);
        acc[mi][1] = __builtin_amdgcn_mfma_f32_16x16x32_f16(a[mi], b[1], acc[mi][1], 0,0,0);
        acc[mi][3] = __builtin_amdgcn_mfma_f32_16x16x32_f16(a[mi], b[2], acc[mi][3], 0,0,0);
      }
    }
    __syncthreads();   // all reads of hl/xl done
    // epilogue
    #pragma unroll
    for (int mi = 0; mi < 4; ++mi){
      #pragma unroll
      for (int rr = 0; rr < 4; ++rr){
        const int rl = mi*16 + r0 + rr;
        const float rg = sigmoidf_(acc[mi][0][rr] + bR);
        const float zg = sigmoidf_(acc[mi][1][rr] + bZ);
        const float ng = tanhf(acc[mi][2][rr] + bNi + rg*(acc[mi][3][rr] + bNh));
        const float hv = (1.0f - zg)*ng + zg*hst[mi][rr];
        hst[mi][rr] = hv;
        hl[rl*LP + col] = (f16)hv;
      }
    }
    __syncthreads();   // hl updated
    // coalesced nt copy LDS -> h1all[t]
    f16* ho = h1all + ((size_t)t*NN + row_base)*H;
    #pragma unroll
    for (int c = 0; c < 2; ++c){
      const int idx = c*1024 + tid;        // 0..2047
      const int row = idx >> 5, seg = idx & 31;
      if (row_base + row < NN)
        __builtin_nontemporal_store(*(const f16x8*)&hl[row*LP + seg*8],
                                    (f16x8*)&ho[(size_t)row*H + seg*8]);
    }
  }
}

// ---------------- layer-2 GRU chain: 64 rows/block, 512 thr = 8 col-groups x 16 cols ----------------
// (R11-measured config: weights once per block-step, no duplicated col-groups.)
__global__ __launch_bounds__(512, 2) void gru2_chain_kernel(
    const f16* __restrict__ x2all, const f16* __restrict__ Wih,
    const f16* __restrict__ Whh, const float* __restrict__ bih,
    const float* __restrict__ bhh, float* __restrict__ h2fin)
{
  constexpr int H   = H2C;     // 128
  constexpr int KX  = H1C;     // 256
  constexpr int LP  = H + 8;   // 136
  constexpr int X2P = KX + 8;  // 264
  __shared__ __align__(16) f16 hl[64*LP];    // 17.4 KB
  __shared__ __align__(16) f16 x2l[64*X2P];  // 33.8 KB

  const int tid  = threadIdx.x;
  const int lane = tid & 63;
  const int w    = tid >> 6;        // 0..7 col group (16 cols each)
  const int lr   = lane & 15;
  const int lk8  = (lane >> 4)*8;
  const int r0   = (lane >> 4)*4;
  const int row_base = blockIdx.x*64;

  for (int k = tid*8; k < 64*LP; k += 512*8)
    *(f16x8*)&hl[k] = (f16x8){0,0,0,0,0,0,0,0};

  int lrow[4];
  #pragma unroll
  for (int mi = 0; mi < 4; ++mi) lrow[mi] = mi*16 + lr;

  const int col = w*16 + lr;
  int bxo[3], bho[3];
  #pragma unroll
  for (int g = 0; g < 3; ++g){
    bxo[g] = (g*H + col)*KX + lk8;
    bho[g] = (g*H + col)*H  + lk8;
  }
  const float bR  = bih[col]       + bhh[col];
  const float bZ  = bih[H+col]     + bhh[H+col];
  const float bNi = bih[2*H+col];
  const float bNh = bhh[2*H+col];

  float hst[4][4] = {};   // [mi][rr]
  __syncthreads();

  for (int t = 0; t < TT; ++t){
    // ---- stage x2 tile (64 rows x 256 f16), nt loads ----
    {
      const f16* xg = x2all + (size_t)t*NN*KX;
      #pragma unroll
      for (int s = 0; s < 4; ++s){
        const int idx = s*512 + tid;       // 0..2047
        const int row = idx >> 5;
        const int sg  = (idx & 31)*8;
        int gr = row_base + row; if (gr >= NN) gr = NN-1;
        f16x8 v = __builtin_nontemporal_load((const f16x8*)&xg[(size_t)gr*KX + sg]);
        *(f16x8*)&x2l[row*X2P + sg] = v;
      }
    }
    __syncthreads();

    f32x4 acc[4][4] = {};   // [mi][0=r,1=z,2=n_x,3=n_h]

    // x2 part, K = 256 (A from LDS)
    #pragma unroll
    for (int k0 = 0; k0 < KX; k0 += 32){
      f16x8 a[4], b[3];
      #pragma unroll
      for (int mi = 0; mi < 4; ++mi) a[mi] = *(const f16x8*)&x2l[lrow[mi]*X2P + k0 + lk8];
      #pragma unroll
      for (int g = 0; g < 3; ++g) b[g] = *(const f16x8*)(Wih + bxo[g] + k0);
      #pragma unroll
      for (int mi = 0; mi < 4; ++mi){
        acc[mi][0] = __builtin_amdgcn_mfma_f32_16x16x32_f16(a[mi], b[0], acc[mi][0], 0,0,0);
        acc[mi][1] = __builtin_amdgcn_mfma_f32_16x16x32_f16(a[mi], b[1], acc[mi][1], 0,0,0);
        acc[mi][2] = __builtin_amdgcn_mfma_f32_16x16x32_f16(a[mi], b[2], acc[mi][2], 0,0,0);
      }
    }
    // h part, K = 128 (A from LDS)
    #pragma unroll
    for (int k0 = 0; k0 < H; k0 += 32){
      f16x8 a[4], b[3];
      #pragma unroll
      for (int mi = 0; mi < 4; ++mi) a[mi] = *(const f16x8*)&hl[lrow[mi]*LP + k0 + lk8];
      #pragma unroll
      for (int g = 0; g < 3; ++g) b[g] = *(const f16x8*)(Whh + bho[g] + k0);
      #pragma unroll
      for (int mi = 0; mi < 4; ++mi){
        acc[mi][0] = __builtin_amdgcn_mfma_f32_16x16x32_f16(a[mi], b[0], acc[mi][0], 0,0,0);
        acc[mi][1] = __builtin_amdgcn_mfma_f32_16x16x32_f16(a[mi], b[1], acc[mi][1], 0,0,0);
        acc[mi][3] = __builtin_amdgcn_mfma_f32_16x16x32_f16(a[mi], b[2], acc[mi][3], 0,0,0);
      }
    }
    __syncthreads();
    #pragma unroll
    for (int mi = 0; mi < 4; ++mi){
      #pragma unroll
      for (int rr = 0; rr < 4; ++rr){
        const int rl = mi*16 + r0 + rr;
        const int growu = row_base + rl;
        const float rg = sigmoidf_(acc[mi][0][rr] + bR);
        const float zg = sigmoidf_(acc[mi][1][rr] + bZ);
        const float ng = tanhf(acc[mi][2][rr] + bNi + rg*(acc[mi][3][rr] + bNh));
        const float hv = (1.0f - zg)*ng + zg*hst[mi][rr];
        hst[mi][rr] = hv;
        hl[rl*LP + col] = (f16)hv;
        if (t == TT-1 && growu < NN)
          h2fin[(size_t)growu*H + col] = hv;
      }
    }
    __syncthreads();
  }
}

// ---------------- batched graph conv: 8 nodes/block, XCD-pinned t-slices ----------------
__global__ __launch_bounds__(512) void conv1_kernel(
    const f16* __restrict__ hall, const int2* __restrict__ pe,
    const int* __restrict__ off, const float* __restrict__ dis,
    const float* __restrict__ bias, f16* __restrict__ outall)
{
  const int b   = blockIdx.x;
  const int xcd = b & 7;
  const int v   = b >> 3;            // 0..3749
  const int tq  = v / 1250;          // 0..2
  const int t   = xcd + 8*tq;
  const int i   = (v - tq*1250)*8 + (threadIdx.x >> 6);
  const int f   = threadIdx.x & 63;  // f16x4 index
  const f16x4* hp = (const f16x4*)(hall + (size_t)t*NN*H1C);
  const float d = dis[i];
  const f16x4 sv = hp[(size_t)i*64 + f];
  float a0 = d*d*(float)sv[0];
  float a1 = d*d*(float)sv[1];
  float a2 = d*d*(float)sv[2];
  float a3 = d*d*(float)sv[3];
  int e = off[i]; const int e2 = off[i+1];
  const i32x2* pev = (const i32x2*)pe;
  for (; e + 8 <= e2; e += 8){
    i32x2 q[8];
    #pragma unroll
    for (int u = 0; u < 8; ++u) q[u] = __builtin_nontemporal_load(&pev[e+u]);
    #pragma unroll
    for (int u = 0; u < 8; ++u){
      const float wq = __int_as_float(q[u][1]);
      const f16x4 vv = hp[(size_t)q[u][0]*64 + f];
      a0 += wq*(float)vv[0]; a1 += wq*(float)vv[1];
      a2 += wq*(float)vv[2]; a3 += wq*(float)vv[3];
    }
  }
  for (; e < e2; ++e){
    const int2 q = pe[e];
    const float wq = __int_as_float(q.y);
    const f16x4 vv = hp[(size_t)q.x*64 + f];
    a0 += wq*(float)vv[0]; a1 += wq*(float)vv[1];
    a2 += wq*(float)vv[2]; a3 += wq*(float)vv[3];
  }
  const float4 bb = ((const float4*)bias)[f];
  a0 = fmaxf(a0 + bb.x, 0.0f);
  a1 = fmaxf(a1 + bb.y, 0.0f);
  a2 = fmaxf(a2 + bb.z, 0.0f);
  a3 = fmaxf(a3 + bb.w, 0.0f);
  f16x4 o; o[0]=(f16)a0; o[1]=(f16)a1; o[2]=(f16)a2; o[3]=(f16)a3;
  __builtin_nontemporal_store(o, (f16x4*)(outall + (size_t)t*NN*H1C) + (size_t)i*64 + f);
}

// conv2: H=128, single t, fp32 in/out
__global__ __launch_bounds__(64) void conv2_kernel(
    const float* __restrict__ h, const int2* __restrict__ pe,
    const int* __restrict__ off, const float* __restrict__ dis,
    const float* __restrict__ bias, float* __restrict__ out)
{
  const int i = blockIdx.x;
  const int f = threadIdx.x;            // float2 index
  const float2* hp = (const float2*)h;
  const float d = dis[i];
  const float2 sv = hp[(size_t)i*64 + f];
  float a0 = d*d*sv.x;
  float a1 = d*d*sv.y;
  int e = off[i]; const int e2 = off[i+1];
  for (; e + 4 <= e2; e += 4){
    int2 q[4];
    #pragma unroll
    for (int u = 0; u < 4; ++u) q[u] = pe[e+u];
    #pragma unroll
    for (int u = 0; u < 4; ++u){
      const float wq = __int_as_float(q[u].y);
      const float2 vv = hp[(size_t)q[u].x*64 + f];
      a0 += wq*vv.x; a1 += wq*vv.y;
    }
  }
  for (; e < e2; ++e){
    const int2 q = pe[e];
    const float wq = __int_as_float(q.y);
    const float2 vv = hp[(size_t)q.x*64 + f];
    a0 += wq*vv.x; a1 += wq*vv.y;
  }
  const float2 bb = ((const float2*)bias)[f];
  ((float2*)out)[(size_t)i*64 + f] = make_float2(a0 + bb.x, a1 + bb.y);
}

// ---------------- final dense + softmax ----------------
__global__ __launch_bounds__(256) void dense_kernel(const float* __restrict__ flat,
    const float* __restrict__ linW, float* __restrict__ logits)
{
  const int j   = blockIdx.x;
  const int tid = threadIdx.x;
  const int Q4  = FLATSZ/4;                  // 320000
  const int CH4 = Q4/64;                     // 5000 (gridDim.y == 64)
  const int s4  = blockIdx.y*CH4;
  const int e4  = s4 + CH4;
  const f32x4* w4 = (const f32x4*)&linW[(size_t)j*FLATSZ];
  const float4* f4 = (const float4*)flat;
  float part = 0.0f;
  for (int i = s4 + tid; i < e4; i += 256){
    const f32x4 a = __builtin_nontemporal_load(&w4[i]);
    const float4 b = f4[i];
    part += a[0]*b.x + a[1]*b.y + a[2]*b.z + a[3]*b.w;
  }
  __shared__ float red[256];
  red[tid] = part; __syncthreads();
  for (int s = 128; s > 0; s >>= 1){
    if (tid < s) red[tid] += red[tid + s];
    __syncthreads();
  }
  if (tid == 0) atomicAdd(&logits[j], red[0]);
}

__global__ __launch_bounds__(128) void softmax_kernel(const float* __restrict__ logits,
    const float* __restrict__ linb, float* __restrict__ out)
{
  __shared__ float red[128];
  const int tid = threadIdx.x;
  const float v = (tid < OUTD) ? logits[tid] + linb[tid] : -INFINITY;
  red[tid] = v; __syncthreads();
  for (int s = 64; s > 0; s >>= 1){
    if (tid < s) red[tid] = fmaxf(red[tid], red[tid + s]);
    __syncthreads();
  }
  const float mx = red[0]; __syncthreads();
  const float e = (tid < OUTD) ? expf(v - mx) : 0.0f;
  red[tid] = e; __syncthreads();
  for (int s = 64; s > 0; s >>= 1){
    if (tid < s) red[tid] += red[tid + s];
    __syncthreads();
  }
  const float inv = 1.0f/red[0];
  if (tid < OUTD) out[tid] = e*inv;
}

// ---------------- launch ----------------

extern "C" void kernel_launch(void* const* d_in, const int* in_sizes, int n_in,
                              void* d_out, int out_size, void* d_ws, size_t ws_size,
                              hipStream_t stream)
{
  const float* x     = (const float*)d_in[0];
  const int*   ei    = (const int*)  d_in[1];
  const float* W_ih1 = (const float*)d_in[2];
  const float* W_hh1 = (const float*)d_in[3];
  const float* b_ih1 = (const float*)d_in[4];
  const float* b_hh1 = (const float*)d_in[5];
  const float* bias1 = (const float*)d_in[6];
  const float* W_ih2 = (const float*)d_in[7];
  const float* W_hh2 = (const float*)d_in[8];
  const float* b_ih2 = (const float*)d_in[9];
  const float* b_hh2 = (const float*)d_in[10];
  const float* bias2 = (const float*)d_in[11];
  const float* lin_W = (const float*)d_in[12];
  const float* lin_b = (const float*)d_in[13];
  float* out = (float*)d_out;
  const int E = in_sizes[1]/2;
  (void)n_in; (void)out_size; (void)ws_size;

  char* p = (char*)d_ws;
  auto alloc = [&](size_t bytes)->void* {
    void* r = (void*)p;
    p += (bytes + 255) & ~(size_t)255;
    return r;
  };
  int*   cnt    = (int*)  alloc((size_t)NN*4);
  int*   cursor = (int*)  alloc((size_t)NN*4);
  int*   offs   = (int*)  alloc((size_t)(NN+1)*4);
  float* dis    = (float*)alloc((size_t)NN*4);
  int2*  pe     = (int2*) alloc((size_t)E*8);
  f16*   h1all  = (f16*)  alloc((size_t)TT*NN*H1C*2);   // 123 MB
  f16*   x2all  = (f16*)  alloc((size_t)TT*NN*H1C*2);   // 123 MB
  float* h2fin  = (float*)alloc((size_t)NN*H2C*4);
  float* out2   = (float*)alloc((size_t)NN*H2C*4);
  f16*   wih1h  = (f16*)  alloc((size_t)3*H1C*DIN*2);
  f16*   whh1h  = (f16*)  alloc((size_t)3*H1C*H1C*2);
  f16*   wih2h  = (f16*)  alloc((size_t)3*H2C*H1C*2);
  f16*   whh2h  = (f16*)  alloc((size_t)3*H2C*H2C*2);
  float* logits = (float*)alloc((size_t)OUTD*4);

  // ---- graph preprocessing ----
  init_kernel   <<<(NN+255)/256, 256, 0, stream>>>(cnt, cursor, logits, NN);
  count_kernel  <<<(E+255)/256, 256, 0, stream>>>(ei, cnt, E);
  dis_kernel    <<<(NN+255)/256, 256, 0, stream>>>(cnt, dis, NN);
  scan_kernel   <<<1, 256, 0, stream>>>(cnt, offs, NN);
  scatter_kernel<<<(E+255)/256, 256, 0, stream>>>(ei, dis, offs, cursor, pe, E);

  // ---- f16 weight casts ----
  cast_f16_kernel<<<((3*H1C*DIN/4)+255)/256, 256, 0, stream>>>((const float4*)W_ih1, (f16x4*)wih1h, 3*H1C*DIN/4);
  cast_f16_kernel<<<((3*H1C*H1C/4)+255)/256, 256, 0, stream>>>((const float4*)W_hh1, (f16x4*)whh1h, 3*H1C*H1C/4);
  cast_f16_kernel<<<((3*H2C*H1C/4)+255)/256, 256, 0, stream>>>((const float4*)W_ih2, (f16x4*)wih2h, 3*H2C*H1C/4);
  cast_f16_kernel<<<((3*H2C*H2C/4)+255)/256, 256, 0, stream>>>((const float4*)W_hh2, (f16x4*)whh2h, 3*H2C*H2C/4);

  const int CB = (NN + 63)/64;   // 157

  // ---- layer-1 chain (R15 config: 1024 thr, 16 col-groups) ----
  gru1_chain_kernel<<<CB, 1024, 0, stream>>>(x, wih1h, whh1h, b_ih1, b_hh1, h1all);

  // ---- batched conv1 (XCD-pinned, 8 nodes/block) ----
  conv1_kernel<<<24*NN/8, 512, 0, stream>>>(h1all, pe, offs, dis, bias1, x2all);

  // ---- layer-2 chain (R11 config: 512 thr, 8 col-groups) ----
  gru2_chain_kernel<<<CB, 512, 0, stream>>>(x2all, wih2h, whh2h, b_ih2, b_hh2, h2fin);

  conv2_kernel<<<NN, 64, 0, stream>>>(h2fin, pe, offs, dis, bias2, out2);
  dense_kernel<<<dim3(OUTD, 64), 256, 0, stream>>>(out2, lin_W, logits);
  softmax_kernel<<<1, 128, 0, stream>>>(logits, lin_b, out);
}

// Round 17
// 1655.007 us; speedup vs baseline: 1.5923x; 1.0410x over previous
//
#include <hip/hip_runtime.h>
#include <math.h>

#define TT   24
#define NN   10000
#define DIN  128
#define H1C  256
#define H2C  128
#define OUTD 100
#define FLATSZ (NN*H2C)

typedef _Float16 f16;
typedef _Float16 f16x4 __attribute__((ext_vector_type(4)));
typedef _Float16 f16x8 __attribute__((ext_vector_type(8)));
typedef float    f32x4 __attribute__((ext_vector_type(4)));
typedef int      i32x2 __attribute__((ext_vector_type(2)));

__device__ __forceinline__ float sigmoidf_(float x){ return 1.0f/(1.0f+expf(-x)); }

// ---------------- small utility kernels ----------------

__global__ __launch_bounds__(256) void cast_f16_kernel(const float4* __restrict__ in,
                                                       f16x4* __restrict__ out, int n4){
  int i = blockIdx.x*256 + threadIdx.x;
  if (i < n4){
    float4 v = in[i];
    f16x4 o; o[0]=(f16)v.x; o[1]=(f16)v.y; o[2]=(f16)v.z; o[3]=(f16)v.w;
    out[i] = o;
  }
}

__global__ __launch_bounds__(256) void init_kernel(int* __restrict__ cnt, int* __restrict__ cursor,
                                                   float* __restrict__ logits, int n){
  int i = blockIdx.x*256 + threadIdx.x;
  if (i < n){ cnt[i] = 0; cursor[i] = 0; }
  if (i < OUTD) logits[i] = 0.0f;
}

__global__ __launch_bounds__(256) void count_kernel(const int* __restrict__ ei, int* __restrict__ cnt, int E){
  int e = blockIdx.x*256 + threadIdx.x;
  if (e < E) atomicAdd(&cnt[ei[E + e]], 1);
}

__global__ __launch_bounds__(256) void dis_kernel(const int* __restrict__ cnt, float* __restrict__ dis, int n){
  int i = blockIdx.x*256 + threadIdx.x;
  if (i < n) dis[i] = rsqrtf((float)(cnt[i] + 1));   // +1 self-loop
}

__global__ __launch_bounds__(256) void scan_kernel(const int* __restrict__ cnt, int* __restrict__ off, int n){
  __shared__ int sums[256];
  const int tid = threadIdx.x;
  const int CH  = 40;
  const int base = tid*CH;
  int s = 0;
  for (int i = 0; i < CH; ++i){ int idx = base + i; if (idx < n) s += cnt[idx]; }
  sums[tid] = s; __syncthreads();
  for (int d = 1; d < 256; d <<= 1){
    int v = (tid >= d) ? sums[tid - d] : 0;
    __syncthreads();
    sums[tid] += v;
    __syncthreads();
  }
  int run = (tid == 0) ? 0 : sums[tid - 1];
  for (int i = 0; i < CH; ++i){
    int idx = base + i;
    if (idx < n){ off[idx] = run; run += cnt[idx]; }
  }
  if (tid == 0) off[n] = sums[255];
}

__global__ __launch_bounds__(256) void scatter_kernel(const int* __restrict__ ei, const float* __restrict__ dis,
                                                      const int* __restrict__ off, int* __restrict__ cursor,
                                                      int2* __restrict__ pe, int E){
  int e = blockIdx.x*256 + threadIdx.x;
  if (e < E){
    int r = ei[e];
    int c = ei[E + e];
    int pos = off[c] + atomicAdd(&cursor[c], 1);
    pe[pos] = make_int2(r, __float_as_int(dis[r]*dis[c]));
  }
}

// ---------------- layer-1 GRU chain: 64 rows/block, 1024 thr = 16 col-groups x 16 cols ----------------
// R16 config + double-buffered x stage: next-t global loads issued under current-t compute.
__global__ __launch_bounds__(1024, 4) void gru1_chain_kernel(
    const float* __restrict__ x, const f16* __restrict__ Wih,
    const f16* __restrict__ Whh, const float* __restrict__ bih,
    const float* __restrict__ bhh, f16* __restrict__ h1all)
{
  constexpr int H  = H1C;      // 256
  constexpr int LP = H + 8;    // 264 f16 pitch (hl)
  constexpr int XP = DIN + 8;  // 136 f16 pitch (xl)
  __shared__ __align__(16) f16 hl[64*LP];      // 33.8 KB
  __shared__ __align__(16) f16 xl[2][64*XP];   // 34.8 KB (double-buffered)

  const int tid  = threadIdx.x;
  const int lane = tid & 63;
  const int w    = tid >> 6;        // 0..15 col group (16 cols each)
  const int lr   = lane & 15;
  const int lk8  = (lane >> 4)*8;
  const int r0   = (lane >> 4)*4;
  const int row_base = blockIdx.x*64;

  for (int k = tid*8; k < 64*LP; k += 1024*8)
    *(f16x8*)&hl[k] = (f16x8){0,0,0,0,0,0,0,0};

  int lrow[4];
  #pragma unroll
  for (int mi = 0; mi < 4; ++mi) lrow[mi] = mi*16 + lr;

  const int col = w*16 + lr;
  int bxo[3], bho[3];
  #pragma unroll
  for (int g = 0; g < 3; ++g){
    bxo[g] = (g*H + col)*DIN + lk8;
    bho[g] = (g*H + col)*H   + lk8;
  }
  const float bR  = bih[col]       + bhh[col];
  const float bZ  = bih[H+col]     + bhh[H+col];
  const float bNi = bih[2*H+col];
  const float bNh = bhh[2*H+col];

  // per-thread stage coordinates (2 chunks of 16B per thread)
  int srow[2], sc4[2], soff[2];
  #pragma unroll
  for (int s = 0; s < 2; ++s){
    const int idx = s*1024 + tid;      // 0..2047
    srow[s] = idx >> 5;
    sc4[s]  = (idx & 31)*4;
    int gr = row_base + srow[s]; if (gr >= NN) gr = NN-1;
    soff[s] = gr*DIN + sc4[s];
  }

  float hst[4][4] = {};   // [mi][rr] fp32 state, thread-owned across t
  // prologue: prefetch t=0 x into registers
  f32x4 xreg[2];
  #pragma unroll
  for (int s = 0; s < 2; ++s)
    xreg[s] = __builtin_nontemporal_load((const f32x4*)&x[soff[s]]);
  __syncthreads();

  for (int t = 0; t < TT; ++t){
    // ---- write staged regs into xl[t&1] ----
    f16* xbuf = xl[t&1];
    #pragma unroll
    for (int s = 0; s < 2; ++s){
      f16x4 o; o[0]=(f16)xreg[s][0]; o[1]=(f16)xreg[s][1]; o[2]=(f16)xreg[s][2]; o[3]=(f16)xreg[s][3];
      *(f16x4*)&xbuf[srow[s]*XP + sc4[s]] = o;
    }
    __syncthreads();   // xl[t&1] ready; hl stable (prev epilogue barrier)

    // ---- issue next-t loads (latency hides under MFMA phase) ----
    {
      const int tn = (t+1 < TT) ? t+1 : t;
      const float* xg = x + (size_t)tn*NN*DIN;
      #pragma unroll
      for (int s = 0; s < 2; ++s)
        xreg[s] = __builtin_nontemporal_load((const f32x4*)&xg[soff[s]]);
    }

    f32x4 acc[4][4] = {};   // [mi][0=r,1=z,2=n_x,3=n_h]

    // x part, K = 128 (A from LDS)
    #pragma unroll
    for (int k0 = 0; k0 < DIN; k0 += 32){
      f16x8 a[4], b[3];
      #pragma unroll
      for (int mi = 0; mi < 4; ++mi) a[mi] = *(const f16x8*)&xbuf[lrow[mi]*XP + k0 + lk8];
      #pragma unroll
      for (int g = 0; g < 3; ++g) b[g] = *(const f16x8*)(Wih + bxo[g] + k0);
      #pragma unroll
      for (int mi = 0; mi < 4; ++mi){
        acc[mi][0] = __builtin_amdgcn_mfma_f32_16x16x32_f16(a[mi], b[0], acc[mi][0], 0,0,0);
        acc[mi][1] = __builtin_amdgcn_mfma_f32_16x16x32_f16(a[mi], b[1], acc[mi][1], 0,0,0);
        acc[mi][2] = __builtin_amdgcn_mfma_f32_16x16x32_f16(a[mi], b[2], acc[mi][2], 0,0,0);
      }
    }
    // h part, K = 256 (A from LDS)
    #pragma unroll
    for (int k0 = 0; k0 < H; k0 += 32){
      f16x8 a[4], b[3];
      #pragma unroll
      for (int mi = 0; mi < 4; ++mi) a[mi] = *(const f16x8*)&hl[lrow[mi]*LP + k0 + lk8];
      #pragma unroll
      for (int g = 0; g < 3; ++g) b[g] = *(const f16x8*)(Whh + bho[g] + k0);
      #pragma unroll
      for (int mi = 0; mi < 4; ++mi){
        acc[mi][0] = __builtin_amdgcn_mfma_f32_16x16x32_f16(a[mi], b[0], acc[mi][0], 0,0,0);
        acc[mi][1] = __builtin_amdgcn_mfma_f32_16x16x32_f16(a[mi], b[1], acc[mi][1], 0,0,0);
        acc[mi][3] = __builtin_amdgcn_mfma_f32_16x16x32_f16(a[mi], b[2], acc[mi][3], 0,0,0);
      }
    }
    __syncthreads();   // all reads of hl done
    // epilogue
    #pragma unroll
    for (int mi = 0; mi < 4; ++mi){
      #pragma unroll
      for (int rr = 0; rr < 4; ++rr){
        const int rl = mi*16 + r0 + rr;
        const float rg = sigmoidf_(acc[mi][0][rr] + bR);
        const float zg = sigmoidf_(acc[mi][1][rr] + bZ);
        const float ng = tanhf(acc[mi][2][rr] + bNi + rg*(acc[mi][3][rr] + bNh));
        const float hv = (1.0f - zg)*ng + zg*hst[mi][rr];
        hst[mi][rr] = hv;
        hl[rl*LP + col] = (f16)hv;
      }
    }
    __syncthreads();   // hl updated
    // coalesced nt copy LDS -> h1all[t]
    f16* ho = h1all + ((size_t)t*NN + row_base)*H;
    #pragma unroll
    for (int c = 0; c < 2; ++c){
      const int idx = c*1024 + tid;        // 0..2047
      const int row = idx >> 5, seg = idx & 31;
      if (row_base + row < NN)
        __builtin_nontemporal_store(*(const f16x8*)&hl[row*LP + seg*8],
                                    (f16x8*)&ho[(size_t)row*H + seg*8]);
    }
  }
}

// ---------------- layer-2 GRU chain: 64 rows/block, 512 thr = 8 col-groups x 16 cols ----------------
// R11 config + double-buffered x2 stage.
__global__ __launch_bounds__(512, 2) void gru2_chain_kernel(
    const f16* __restrict__ x2all, const f16* __restrict__ Wih,
    const f16* __restrict__ Whh, const float* __restrict__ bih,
    const float* __restrict__ bhh, float* __restrict__ h2fin)
{
  constexpr int H   = H2C;     // 128
  constexpr int KX  = H1C;     // 256
  constexpr int LP  = H + 8;   // 136
  constexpr int X2P = KX + 8;  // 264
  __shared__ __align__(16) f16 hl[64*LP];       // 17.4 KB
  __shared__ __align__(16) f16 x2l[2][64*X2P];  // 67.6 KB (double-buffered)

  const int tid  = threadIdx.x;
  const int lane = tid & 63;
  const int w    = tid >> 6;        // 0..7 col group (16 cols each)
  const int lr   = lane & 15;
  const int lk8  = (lane >> 4)*8;
  const int r0   = (lane >> 4)*4;
  const int row_base = blockIdx.x*64;

  for (int k = tid*8; k < 64*LP; k += 512*8)
    *(f16x8*)&hl[k] = (f16x8){0,0,0,0,0,0,0,0};

  int lrow[4];
  #pragma unroll
  for (int mi = 0; mi < 4; ++mi) lrow[mi] = mi*16 + lr;

  const int col = w*16 + lr;
  int bxo[3], bho[3];
  #pragma unroll
  for (int g = 0; g < 3; ++g){
    bxo[g] = (g*H + col)*KX + lk8;
    bho[g] = (g*H + col)*H  + lk8;
  }
  const float bR  = bih[col]       + bhh[col];
  const float bZ  = bih[H+col]     + bhh[H+col];
  const float bNi = bih[2*H+col];
  const float bNh = bhh[2*H+col];

  // stage coordinates: 4 chunks of 16B per thread
  int srow[4], ssg[4], soff[4];
  #pragma unroll
  for (int s = 0; s < 4; ++s){
    const int idx = s*512 + tid;       // 0..2047
    srow[s] = idx >> 5;
    ssg[s]  = (idx & 31)*8;
    int gr = row_base + srow[s]; if (gr >= NN) gr = NN-1;
    soff[s] = gr*KX + ssg[s];
  }

  float hst[4][4] = {};   // [mi][rr]
  f16x8 xreg[4];
  #pragma unroll
  for (int s = 0; s < 4; ++s)
    xreg[s] = __builtin_nontemporal_load((const f16x8*)&x2all[soff[s]]);
  __syncthreads();

  for (int t = 0; t < TT; ++t){
    f16* xbuf = x2l[t&1];
    #pragma unroll
    for (int s = 0; s < 4; ++s)
      *(f16x8*)&xbuf[srow[s]*X2P + ssg[s]] = xreg[s];
    __syncthreads();

    {
      const int tn = (t+1 < TT) ? t+1 : t;
      const f16* xg = x2all + (size_t)tn*NN*KX;
      #pragma unroll
      for (int s = 0; s < 4; ++s)
        xreg[s] = __builtin_nontemporal_load((const f16x8*)&xg[soff[s]]);
    }

    f32x4 acc[4][4] = {};   // [mi][0=r,1=z,2=n_x,3=n_h]

    // x2 part, K = 256 (A from LDS)
    #pragma unroll
    for (int k0 = 0; k0 < KX; k0 += 32){
      f16x8 a[4], b[3];
      #pragma unroll
      for (int mi = 0; mi < 4; ++mi) a[mi] = *(const f16x8*)&xbuf[lrow[mi]*X2P + k0 + lk8];
      #pragma unroll
      for (int g = 0; g < 3; ++g) b[g] = *(const f16x8*)(Wih + bxo[g] + k0);
      #pragma unroll
      for (int mi = 0; mi < 4; ++mi){
        acc[mi][0] = __builtin_amdgcn_mfma_f32_16x16x32_f16(a[mi], b[0], acc[mi][0], 0,0,0);
        acc[mi][1] = __builtin_amdgcn_mfma_f32_16x16x32_f16(a[mi], b[1], acc[mi][1], 0,0,0);
        acc[mi][2] = __builtin_amdgcn_mfma_f32_16x16x32_f16(a[mi], b[2], acc[mi][2], 0,0,0);
      }
    }
    // h part, K = 128 (A from LDS)
    #pragma unroll
    for (int k0 = 0; k0 < H; k0 += 32){
      f16x8 a[4], b[3];
      #pragma unroll
      for (int mi = 0; mi < 4; ++mi) a[mi] = *(const f16x8*)&hl[lrow[mi]*LP + k0 + lk8];
      #pragma unroll
      for (int g = 0; g < 3; ++g) b[g] = *(const f16x8*)(Whh + bho[g] + k0);
      #pragma unroll
      for (int mi = 0; mi < 4; ++mi){
        acc[mi][0] = __builtin_amdgcn_mfma_f32_16x16x32_f16(a[mi], b[0], acc[mi][0], 0,0,0);
        acc[mi][1] = __builtin_amdgcn_mfma_f32_16x16x32_f16(a[mi], b[1], acc[mi][1], 0,0,0);
        acc[mi][3] = __builtin_amdgcn_mfma_f32_16x16x32_f16(a[mi], b[2], acc[mi][3], 0,0,0);
      }
    }
    __syncthreads();
    #pragma unroll
    for (int mi = 0; mi < 4; ++mi){
      #pragma unroll
      for (int rr = 0; rr < 4; ++rr){
        const int rl = mi*16 + r0 + rr;
        const int growu = row_base + rl;
        const float rg = sigmoidf_(acc[mi][0][rr] + bR);
        const float zg = sigmoidf_(acc[mi][1][rr] + bZ);
        const float ng = tanhf(acc[mi][2][rr] + bNi + rg*(acc[mi][3][rr] + bNh));
        const float hv = (1.0f - zg)*ng + zg*hst[mi][rr];
        hst[mi][rr] = hv;
        hl[rl*LP + col] = (f16)hv;
        if (t == TT-1 && growu < NN)
          h2fin[(size_t)growu*H + col] = hv;
      }
    }
    __syncthreads();
  }
}

// ---------------- batched graph conv: 8 nodes/block, XCD-pinned t-slices ----------------
__global__ __launch_bounds__(512) void conv1_kernel(
    const f16* __restrict__ hall, const int2* __restrict__ pe,
    const int* __restrict__ off, const float* __restrict__ dis,
    const float* __restrict__ bias, f16* __restrict__ outall)
{
  const int b   = blockIdx.x;
  const int xcd = b & 7;
  const int v   = b >> 3;            // 0..3749
  const int tq  = v / 1250;          // 0..2
  const int t   = xcd + 8*tq;
  const int i   = (v - tq*1250)*8 + (threadIdx.x >> 6);
  const int f   = threadIdx.x & 63;  // f16x4 index
  const f16x4* hp = (const f16x4*)(hall + (size_t)t*NN*H1C);
  const float d = dis[i];
  const f16x4 sv = hp[(size_t)i*64 + f];
  float a0 = d*d*(float)sv[0];
  float a1 = d*d*(float)sv[1];
  float a2 = d*d*(float)sv[2];
  float a3 = d*d*(float)sv[3];
  int e = off[i]; const int e2 = off[i+1];
  const i32x2* pev = (const i32x2*)pe;
  for (; e + 8 <= e2; e += 8){
    i32x2 q[8];
    #pragma unroll
    for (int u = 0; u < 8; ++u) q[u] = __builtin_nontemporal_load(&pev[e+u]);
    #pragma unroll
    for (int u = 0; u < 8; ++u){
      const float wq = __int_as_float(q[u][1]);
      const f16x4 vv = hp[(size_t)q[u][0]*64 + f];
      a0 += wq*(float)vv[0]; a1 += wq*(float)vv[1];
      a2 += wq*(float)vv[2]; a3 += wq*(float)vv[3];
    }
  }
  for (; e < e2; ++e){
    const int2 q = pe[e];
    const float wq = __int_as_float(q.y);
    const f16x4 vv = hp[(size_t)q.x*64 + f];
    a0 += wq*(float)vv[0]; a1 += wq*(float)vv[1];
    a2 += wq*(float)vv[2]; a3 += wq*(float)vv[3];
  }
  const float4 bb = ((const float4*)bias)[f];
  a0 = fmaxf(a0 + bb.x, 0.0f);
  a1 = fmaxf(a1 + bb.y, 0.0f);
  a2 = fmaxf(a2 + bb.z, 0.0f);
  a3 = fmaxf(a3 + bb.w, 0.0f);
  f16x4 o; o[0]=(f16)a0; o[1]=(f16)a1; o[2]=(f16)a2; o[3]=(f16)a3;
  __builtin_nontemporal_store(o, (f16x4*)(outall + (size_t)t*NN*H1C) + (size_t)i*64 + f);
}

// conv2: H=128, single t, fp32 in/out
__global__ __launch_bounds__(64) void conv2_kernel(
    const float* __restrict__ h, const int2* __restrict__ pe,
    const int* __restrict__ off, const float* __restrict__ dis,
    const float* __restrict__ bias, float* __restrict__ out)
{
  const int i = blockIdx.x;
  const int f = threadIdx.x;            // float2 index
  const float2* hp = (const float2*)h;
  const float d = dis[i];
  const float2 sv = hp[(size_t)i*64 + f];
  float a0 = d*d*sv.x;
  float a1 = d*d*sv.y;
  int e = off[i]; const int e2 = off[i+1];
  for (; e + 4 <= e2; e += 4){
    int2 q[4];
    #pragma unroll
    for (int u = 0; u < 4; ++u) q[u] = pe[e+u];
    #pragma unroll
    for (int u = 0; u < 4; ++u){
      const float wq = __int_as_float(q[u].y);
      const float2 vv = hp[(size_t)q[u].x*64 + f];
      a0 += wq*vv.x; a1 += wq*vv.y;
    }
  }
  for (; e < e2; ++e){
    const int2 q = pe[e];
    const float wq = __int_as_float(q.y);
    const float2 vv = hp[(size_t)q.x*64 + f];
    a0 += wq*vv.x; a1 += wq*vv.y;
  }
  const float2 bb = ((const float2*)bias)[f];
  ((float2*)out)[(size_t)i*64 + f] = make_float2(a0 + bb.x, a1 + bb.y);
}

// ---------------- final dense + softmax ----------------
__global__ __launch_bounds__(256) void dense_kernel(const float* __restrict__ flat,
    const float* __restrict__ linW, float* __restrict__ logits)
{
  const int j   = blockIdx.x;
  const int tid = threadIdx.x;
  const int Q4  = FLATSZ/4;                  // 320000
  const int CH4 = Q4/64;                     // 5000 (gridDim.y == 64)
  const int s4  = blockIdx.y*CH4;
  const int e4  = s4 + CH4;
  const f32x4* w4 = (const f32x4*)&linW[(size_t)j*FLATSZ];
  const float4* f4 = (const float4*)flat;
  float part = 0.0f;
  for (int i = s4 + tid; i < e4; i += 256){
    const f32x4 a = __builtin_nontemporal_load(&w4[i]);
    const float4 b = f4[i];
    part += a[0]*b.x + a[1]*b.y + a[2]*b.z + a[3]*b.w;
  }
  __shared__ float red[256];
  red[tid] = part; __syncthreads();
  for (int s = 128; s > 0; s >>= 1){
    if (tid < s) red[tid] += red[tid + s];
    __syncthreads();
  }
  if (tid == 0) atomicAdd(&logits[j], red[0]);
}

__global__ __launch_bounds__(128) void softmax_kernel(const float* __restrict__ logits,
    const float* __restrict__ linb, float* __restrict__ out)
{
  __shared__ float red[128];
  const int tid = threadIdx.x;
  const float v = (tid < OUTD) ? logits[tid] + linb[tid] : -INFINITY;
  red[tid] = v; __syncthreads();
  for (int s = 64; s > 0; s >>= 1){
    if (tid < s) red[tid] = fmaxf(red[tid], red[tid + s]);
    __syncthreads();
  }
  const float mx = red[0]; __syncthreads();
  const float e = (tid < OUTD) ? expf(v - mx) : 0.0f;
  red[tid] = e; __syncthreads();
  for (int s = 64; s > 0; s >>= 1){
    if (tid < s) red[tid] += red[tid + s];
    __syncthreads();
  }
  const float inv = 1.0f/red[0];
  if (tid < OUTD) out[tid] = e*inv;
}

// ---------------- launch ----------------

extern "C" void kernel_launch(void* const* d_in, const int* in_sizes, int n_in,
                              void* d_out, int out_size, void* d_ws, size_t ws_size,
                              hipStream_t stream)
{
  const float* x     = (const float*)d_in[0];
  const int*   ei    = (const int*)  d_in[1];
  const float* W_ih1 = (const float*)d_in[2];
  const float* W_hh1 = (const float*)d_in[3];
  const float* b_ih1 = (const float*)d_in[4];
  const float* b_hh1 = (const float*)d_in[5];
  const float* bias1 = (const float*)d_in[6];
  const float* W_ih2 = (const float*)d_in[7];
  const float* W_hh2 = (const float*)d_in[8];
  const float* b_ih2 = (const float*)d_in[9];
  const float* b_hh2 = (const float*)d_in[10];
  const float* bias2 = (const float*)d_in[11];
  const float* lin_W = (const float*)d_in[12];
  const float* lin_b = (const float*)d_in[13];
  float* out = (float*)d_out;
  const int E = in_sizes[1]/2;
  (void)n_in; (void)out_size; (void)ws_size;

  char* p = (char*)d_ws;
  auto alloc = [&](size_t bytes)->void* {
    void* r = (void*)p;
    p += (bytes + 255) & ~(size_t)255;
    return r;
  };
  int*   cnt    = (int*)  alloc((size_t)NN*4);
  int*   cursor = (int*)  alloc((size_t)NN*4);
  int*   offs   = (int*)  alloc((size_t)(NN+1)*4);
  float* dis    = (float*)alloc((size_t)NN*4);
  int2*  pe     = (int2*) alloc((size_t)E*8);
  f16*   h1all  = (f16*)  alloc((size_t)TT*NN*H1C*2);   // 123 MB
  f16*   x2all  = (f16*)  alloc((size_t)TT*NN*H1C*2);   // 123 MB
  float* h2fin  = (float*)alloc((size_t)NN*H2C*4);
  float* out2   = (float*)alloc((size_t)NN*H2C*4);
  f16*   wih1h  = (f16*)  alloc((size_t)3*H1C*DIN*2);
  f16*   whh1h  = (f16*)  alloc((size_t)3*H1C*H1C*2);
  f16*   wih2h  = (f16*)  alloc((size_t)3*H2C*H1C*2);
  f16*   whh2h  = (f16*)  alloc((size_t)3*H2C*H2C*2);
  float* logits = (float*)alloc((size_t)OUTD*4);

  // ---- graph preprocessing ----
  init_kernel   <<<(NN+255)/256, 256, 0, stream>>>(cnt, cursor, logits, NN);
  count_kernel  <<<(E+255)/256, 256, 0, stream>>>(ei, cnt, E);
  dis_kernel    <<<(NN+255)/256, 256, 0, stream>>>(cnt, dis, NN);
  scan_kernel   <<<1, 256, 0, stream>>>(cnt, offs, NN);
  scatter_kernel<<<(E+255)/256, 256, 0, stream>>>(ei, dis, offs, cursor, pe, E);

  // ---- f16 weight casts ----
  cast_f16_kernel<<<((3*H1C*DIN/4)+255)/256, 256, 0, stream>>>((const float4*)W_ih1, (f16x4*)wih1h, 3*H1C*DIN/4);
  cast_f16_kernel<<<((3*H1C*H1C/4)+255)/256, 256, 0, stream>>>((const float4*)W_hh1, (f16x4*)whh1h, 3*H1C*H1C/4);
  cast_f16_kernel<<<((3*H2C*H1C/4)+255)/256, 256, 0, stream>>>((const float4*)W_ih2, (f16x4*)wih2h, 3*H2C*H1C/4);
  cast_f16_kernel<<<((3*H2C*H2C/4)+255)/256, 256, 0, stream>>>((const float4*)W_hh2, (f16x4*)whh2h, 3*H2C*H2C/4);

  const int CB = (NN + 63)/64;   // 157

  // ---- layer-1 chain (1024 thr, 16 col-groups, pipelined x stage) ----
  gru1_chain_kernel<<<CB, 1024, 0, stream>>>(x, wih1h, whh1h, b_ih1, b_hh1, h1all);

  // ---- batched conv1 (XCD-pinned, 8 nodes/block) ----
  conv1_kernel<<<24*NN/8, 512, 0, stream>>>(h1all, pe, offs, dis, bias1, x2all);

  // ---- layer-2 chain (512 thr, 8 col-groups, pipelined x2 stage) ----
  gru2_chain_kernel<<<CB, 512, 0, stream>>>(x2all, wih2h, whh2h, b_ih2, b_hh2, h2fin);

  conv2_kernel<<<NN, 64, 0, stream>>>(h2fin, pe, offs, dis, bias2, out2);
  dense_kernel<<<dim3(OUTD, 64), 256, 0, stream>>>(out2, lin_W, logits);
  softmax_kernel<<<1, 128, 0, stream>>>(logits, lin_b, out);
}